// Round 10
// baseline (186.199 us; speedup 1.0000x reference)
//
#include <hip/hip_runtime.h>
#include <hip/hip_bf16.h>

#define B_  2
#define S_  2048
#define E_  768
#define H_  12
#define DK_ 64
#define NQ_ 8
#define FF_ 3072
#define EPS_ 1e-5f

typedef __attribute__((ext_vector_type(8))) short short8;
typedef __attribute__((ext_vector_type(4))) float f32x4;
typedef __hip_bfloat16 bf16;

__device__ __forceinline__ bf16 f2bh(float f) { return __float2bfloat16(f); }
__device__ __forceinline__ short f2b(float f) {
    bf16 h = __float2bfloat16(f);
    return *reinterpret_cast<short*>(&h);
}

// XOR swizzle, 16B-block granular, within a 64-elem bf16 (128B) LDS row.
__device__ __forceinline__ int swz(int row, int col) {
    return (col & 7) | ((((col >> 3) ^ (row & 7)) & 7) << 3);
}

__device__ __forceinline__ f32x4 mfma16(short8 a, short8 b, f32x4 c) {
    return __builtin_amdgcn_mfma_f32_16x16x32_bf16(a, b, c, 0, 0, 0);
}

// ---------------------------------------------------------------------------
// prep: xb = bf16(x) row-major AND xT[b][e][s] transposed. One pass.
// ---------------------------------------------------------------------------
__global__ __launch_bounds__(256) void prep_xall(const float* __restrict__ x,
                                                 bf16* __restrict__ xb,
                                                 bf16* __restrict__ xT) {
    __shared__ float tile[32][33];
    int e0 = blockIdx.x * 32, s0 = blockIdx.y * 32;
    int tx = threadIdx.x & 31, ty = threadIdx.x >> 5;
    int b = s0 >> 11, sl0 = s0 & 2047;
#pragma unroll
    for (int i = 0; i < 4; i++) {
        int row = ty + i * 8;
        float v = x[(size_t)(s0 + row) * E_ + e0 + tx];
        tile[row][tx] = v;
        xb[(size_t)(s0 + row) * E_ + e0 + tx] = f2bh(v);
    }
    __syncthreads();
#pragma unroll
    for (int i = 0; i < 4; i++) {
        int row = ty + i * 8;
        xT[((size_t)b * E_ + e0 + row) * S_ + sl0 + tx] = f2bh(tile[tx][row]);
    }
}

// ---------------------------------------------------------------------------
// prep: xb = bf16(x)  (fallback path only)
// ---------------------------------------------------------------------------
__global__ __launch_bounds__(256) void prep_cvt(const float* __restrict__ x,
                                                bf16* __restrict__ xb, int n4) {
    int i = blockIdx.x * 256 + threadIdx.x;
    if (i >= n4) return;
    float4 f = *(const float4*)(x + (size_t)i * 4);
    short4 sv;
    sv.x = f2b(f.x); sv.y = f2b(f.y); sv.z = f2b(f.z); sv.w = f2b(f.w);
    *(short4*)((short*)xb + (size_t)i * 4) = sv;
}

// ---------------------------------------------------------------------------
// prep: WT[N][K] = bf16(W[K][N])
// ---------------------------------------------------------------------------
__global__ __launch_bounds__(256) void transpose_cvt(const float* __restrict__ W,
                                                     bf16* __restrict__ WT,
                                                     int K, int N) {
    __shared__ float tile[32][33];
    int k0 = blockIdx.y * 32, n0 = blockIdx.x * 32;
    int tx = threadIdx.x & 31, ty = threadIdx.x >> 5;
#pragma unroll
    for (int i = 0; i < 4; i++) {
        int row = ty + i * 8;
        tile[row][tx] = W[(size_t)(k0 + row) * N + n0 + tx];
    }
    __syncthreads();
#pragma unroll
    for (int i = 0; i < 4; i++) {
        int row = ty + i * 8;
        WT[(size_t)(n0 + row) * K + k0 + tx] = f2bh(tile[tx][row]);
    }
}

// ---------------------------------------------------------------------------
// prep: W1bT[k][i] = bf16(W1[i][k])
// ---------------------------------------------------------------------------
__global__ __launch_bounds__(256) void prep_w1t(const float* __restrict__ W1,
                                                bf16* __restrict__ W1bT) {
    int k = blockIdx.x * 256 + threadIdx.x;
    if (k >= FF_) return;
    short8 v;
#pragma unroll
    for (int i = 0; i < NQ_; i++) v[i] = f2b(W1[(size_t)i * FF_ + k]);
    *(short8*)(W1bT + (size_t)k * NQ_) = v;
}

// ---------------------------------------------------------------------------
// MFMA flash attention (unchanged from round 9 — known good).
// ---------------------------------------------------------------------------
template<bool XT>
__global__ __launch_bounds__(256) void attn_kernel(const bf16* __restrict__ xb,
                                                   const bf16* __restrict__ xT,
                                                   bf16* __restrict__ out) {
    const int qtiles = S_ / 64;                  // 32
    const int nwg = B_ * H_ * qtiles;            // 768
    int o = blockIdx.x;
    int blk = (o & 7) * (nwg >> 3) + (o >> 3);
    int qt = blk % qtiles;
    int hh = (blk / qtiles) % H_;
    int bb = blk / (qtiles * H_);
    const bf16* base = xb + (size_t)bb * S_ * E_ + hh * DK_;
    const bf16* baseT = xT + ((size_t)bb * E_ + hh * DK_) * S_;

    __shared__ __align__(16) bf16 Ks[64][64];
    __shared__ __align__(16) bf16 Vt[64][64];
    __shared__ __align__(16) bf16 Pl[4][16][64];

    int t = threadIdx.x;
    int w = t >> 6, l = t & 63, c = l & 15, g = l >> 4;

    short8 qf[2];
    {
        const bf16* qp = base + (size_t)(qt * 64 + w * 16 + c) * E_;
        qf[0] = *(const short8*)(qp + g * 8);
        qf[1] = *(const short8*)(qp + 32 + g * 8);
    }

    f32x4 oacc[4];
    float l_part[4];
#pragma unroll
    for (int n = 0; n < 4; n++) { oacc[n] = (f32x4){0.f, 0.f, 0.f, 0.f}; l_part[n] = 0.f; }

    int skey = t & 63;
    int scb0 = t >> 6;

    short8 preK[2], preV[2];
#pragma unroll
    for (int it = 0; it < 2; it++) {
        preK[it] = *(const short8*)(base + (size_t)skey * E_ + (scb0 + it * 4) * 8);
        if (XT)
            preV[it] = *(const short8*)(baseT + (size_t)skey * S_ + (scb0 + it * 4) * 8);
    }

    for (int kt = 0; kt < S_ / 64; kt++) {
#pragma unroll
        for (int it = 0; it < 2; it++) {
            int cb = scb0 + it * 4;
            *(short8*)&Ks[skey][swz(skey, cb * 8)] = preK[it];
            if (XT) {
                *(short8*)&Vt[skey][swz(skey, cb * 8)] = preV[it];
            } else {
#pragma unroll
                for (int j = 0; j < 8; j++) {
                    int d = cb * 8 + j;
                    short sv = preK[it][j];
                    Vt[d][swz(d, skey)] = *reinterpret_cast<bf16*>(&sv);
                }
            }
        }
        __syncthreads();

        if (kt + 1 < S_ / 64) {
#pragma unroll
            for (int it = 0; it < 2; it++) {
                preK[it] = *(const short8*)(base + (size_t)((kt + 1) * 64 + skey) * E_ + (scb0 + it * 4) * 8);
                if (XT)
                    preV[it] = *(const short8*)(baseT + (size_t)skey * S_ + (kt + 1) * 64 + (scb0 + it * 4) * 8);
            }
        }

        f32x4 sfr[4];
        __builtin_amdgcn_s_setprio(1);
#pragma unroll
        for (int n = 0; n < 4; n++) {
            sfr[n] = (f32x4){0.f, 0.f, 0.f, 0.f};
#pragma unroll
            for (int kh = 0; kh < 2; kh++) {
                const short8 bfr = *(const short8*)&Ks[n * 16 + c][swz(n * 16 + c, kh * 32 + g * 8)];
                sfr[n] = mfma16(qf[kh], bfr, sfr[n]);
            }
        }
        __builtin_amdgcn_s_setprio(0);
#pragma unroll
        for (int jj = 0; jj < 4; jj++) {
            float pv[4];
#pragma unroll
            for (int n = 0; n < 4; n++)
                pv[n] = exp2f(sfr[n][jj] * 0.18033688f);   // log2(e)/8
            l_part[jj] += (pv[0] + pv[1]) + (pv[2] + pv[3]);
            int r = g * 4 + jj;
#pragma unroll
            for (int n = 0; n < 4; n++)
                Pl[w][r][swz(r, n * 16 + c)] = f2bh(pv[n]);
        }

        __builtin_amdgcn_s_setprio(1);
#pragma unroll
        for (int ks = 0; ks < 2; ks++) {
            short8 vb[4];
#pragma unroll
            for (int dn = 0; dn < 4; dn++)
                vb[dn] = *(const short8*)&Vt[dn * 16 + c][swz(dn * 16 + c, ks * 32 + g * 8)];
            const short8 pa = *(const short8*)&Pl[w][c][swz(c, ks * 32 + g * 8)];
#pragma unroll
            for (int dn = 0; dn < 4; dn++)
                oacc[dn] = mfma16(pa, vb[dn], oacc[dn]);
        }
        __builtin_amdgcn_s_setprio(0);
        __syncthreads();
    }

#pragma unroll
    for (int jj = 0; jj < 4; jj++) {
        float lv = l_part[jj];
#pragma unroll
        for (int msk = 1; msk < 16; msk <<= 1) lv += __shfl_xor(lv, msk);
        float inv = 1.f / lv;
        size_t ro = ((size_t)bb * S_ + qt * 64 + w * 16 + g * 4 + jj) * E_ + hh * DK_;
#pragma unroll
        for (int dn = 0; dn < 4; dn++)
            out[ro + dn * 16 + c] = f2bh(oacc[dn][jj] * inv);
    }
}

// ---------------------------------------------------------------------------
// bf16 GEMM (unchanged from round 8/9 — known good).
// ---------------------------------------------------------------------------
__global__ __launch_bounds__(256) void gemm_bf16(const bf16* __restrict__ A,
                                                 const bf16* __restrict__ BT,
                                                 const float* __restrict__ bias,
                                                 bf16* __restrict__ C,
                                                 int M, int N, int K) {
    __shared__ __align__(16) bf16 As2[2][64][64];
    __shared__ __align__(16) bf16 Bs2[2][64][64];
    int nbx = gridDim.x, nwg = nbx * gridDim.y;
    int id = blockIdx.y * nbx + blockIdx.x;
    int id2 = (nwg & 7) ? id : ((id & 7) * (nwg >> 3) + (id >> 3));
    int row0 = (id2 / nbx) * 64, col0 = (id2 % nbx) * 64;
    int t = threadIdx.x, w = t >> 6, l = t & 63, c = l & 15, g = l >> 4;

    f32x4 acc[4];
#pragma unroll
    for (int n = 0; n < 4; n++) acc[n] = (f32x4){0.f, 0.f, 0.f, 0.f};

    int srow = t & 63, scb = t >> 6;
    const bf16* ap = A + (size_t)(row0 + srow) * K;
    const bf16* bp = BT + (size_t)(col0 + srow) * K;

    short8 pA0, pA1, pB0, pB1;
    pA0 = *(const short8*)(ap + scb * 8);
    pA1 = *(const short8*)(ap + (scb + 4) * 8);
    pB0 = *(const short8*)(bp + scb * 8);
    pB1 = *(const short8*)(bp + (scb + 4) * 8);
    *(short8*)&As2[0][srow][swz(srow, scb * 8)] = pA0;
    *(short8*)&As2[0][srow][swz(srow, (scb + 4) * 8)] = pA1;
    *(short8*)&Bs2[0][srow][swz(srow, scb * 8)] = pB0;
    *(short8*)&Bs2[0][srow][swz(srow, (scb + 4) * 8)] = pB1;
    if (64 < K) {
        pA0 = *(const short8*)(ap + 64 + scb * 8);
        pA1 = *(const short8*)(ap + 64 + (scb + 4) * 8);
        pB0 = *(const short8*)(bp + 64 + scb * 8);
        pB1 = *(const short8*)(bp + 64 + (scb + 4) * 8);
    }
    __syncthreads();

    int cur = 0;
    for (int k0 = 0; k0 < K; k0 += 64, cur ^= 1) {
        int nxt = cur ^ 1;
        if (k0 + 64 < K) {
            *(short8*)&As2[nxt][srow][swz(srow, scb * 8)] = pA0;
            *(short8*)&As2[nxt][srow][swz(srow, (scb + 4) * 8)] = pA1;
            *(short8*)&Bs2[nxt][srow][swz(srow, scb * 8)] = pB0;
            *(short8*)&Bs2[nxt][srow][swz(srow, (scb + 4) * 8)] = pB1;
        }
        if (k0 + 128 < K) {
            pA0 = *(const short8*)(ap + k0 + 128 + scb * 8);
            pA1 = *(const short8*)(ap + k0 + 128 + (scb + 4) * 8);
            pB0 = *(const short8*)(bp + k0 + 128 + scb * 8);
            pB1 = *(const short8*)(bp + k0 + 128 + (scb + 4) * 8);
        }
#pragma unroll
        for (int kh = 0; kh < 2; kh++) {
            const short8 af = *(const short8*)&As2[cur][w * 16 + c][swz(w * 16 + c, kh * 32 + g * 8)];
#pragma unroll
            for (int n = 0; n < 4; n++) {
                const short8 bfr = *(const short8*)&Bs2[cur][n * 16 + c][swz(n * 16 + c, kh * 32 + g * 8)];
                acc[n] = mfma16(af, bfr, acc[n]);
            }
        }
        __syncthreads();
    }
#pragma unroll
    for (int jj = 0; jj < 4; jj++) {
        int row = row0 + w * 16 + g * 4 + jj;
#pragma unroll
        for (int n = 0; n < 4; n++) {
            int col = col0 + n * 16 + c;
            C[(size_t)row * N + col] = f2bh(acc[n][jj] + bias[col]);
        }
    }
}

// ---------------------------------------------------------------------------
// GEMM2, h-PIPELINED one K-step ahead:
//   step k: [write Bs[nxt]] [prefetch B k+2] [h-MFMA(k+1) from regs]
//           [main MFMA on As[cur],Bs[cur]] [relu->As[nxt]] [load W1/b1 k+2]
//           [barrier]
// As is wave-local (rows w*16..+15), double-buffered; W1 frags loaded
// per-wave from global (L2-hot 49KB) — no W1t LDS, no same-step As chain.
// ---------------------------------------------------------------------------
__global__ __launch_bounds__(256) void gemm2_mfma(const float* __restrict__ xln,
                                                  const float* __restrict__ ry,
                                                  const bf16* __restrict__ W1bT,
                                                  const float* __restrict__ b1,
                                                  const bf16* __restrict__ W2bT,
                                                  const float* __restrict__ b2,
                                                  bf16* __restrict__ C) {
    __shared__ __align__(16) bf16 As[2][64][64];
    __shared__ __align__(16) bf16 Bs[2][64][64];
    __shared__ __align__(16) bf16 qm_s[64][8];
    const int nbx = E_ / 64;                    // 12
    const int nwg = nbx * (B_ * S_ / 64);       // 768
    const int NS = FF_ / 64;                    // 48
    int id = blockIdx.y * nbx + blockIdx.x;
    int id2 = (id & 7) * (nwg >> 3) + (id >> 3);
    int row0 = (id2 / nbx) * 64, col0 = (id2 % nbx) * 64;
    int t = threadIdx.x, w = t >> 6, l = t & 63, c = l & 15, g = l >> 4;

    if (t < 64) {
        const float* xp = xln + (size_t)(row0 + t) * E_;
#pragma unroll
        for (int i = 0; i < NQ_; i++)
            qm_s[t][i] = f2bh(cosf(xp[i]) * cosf(ry[i]));
    }

    f32x4 acc[4];
#pragma unroll
    for (int n = 0; n < 4; n++) acc[n] = (f32x4){0.f, 0.f, 0.f, 0.f};

    int srow = t & 63, scb = t >> 6;
    const bf16* brow_p = W2bT + (size_t)(col0 + srow) * FF_;

    const short8 zz = {0, 0, 0, 0, 0, 0, 0, 0};
    const f32x4 zero4 = {0.f, 0.f, 0.f, 0.f};

    // stage Bs[0]; prefetch B for step 1
    short8 preB0, preB1;
    preB0 = *(const short8*)(brow_p + scb * 8);
    preB1 = *(const short8*)(brow_p + (scb + 4) * 8);
    *(short8*)&Bs[0][srow][swz(srow, scb * 8)] = preB0;
    *(short8*)&Bs[0][srow][swz(srow, (scb + 4) * 8)] = preB1;
    preB0 = *(const short8*)(brow_p + 64 + scb * 8);
    preB1 = *(const short8*)(brow_p + 64 + (scb + 4) * 8);
    __syncthreads();   // qm_s + Bs[0] visible

    // loop-invariant qm A-fragment (g==0 lanes carry the 8 real k's)
    short8 aq = zz;
    if (g == 0) aq = *(const short8*)&qm_s[w * 16 + c][0];

    // W1 B-fragments + b1 for step 0 (direct from global; L2-hot)
    short8 bwN[4];
    float b1N[4];
#pragma unroll
    for (int n = 0; n < 4; n++) {
        bwN[n] = zz;
        if (g == 0) bwN[n] = *(const short8*)(W1bT + (size_t)(n * 16 + c) * NQ_);
        b1N[n] = b1[n * 16 + c];
    }
    // h(0) -> As[0]  (wave-local)
#pragma unroll
    for (int n = 0; n < 4; n++) {
        f32x4 hfr = mfma16(aq, bwN[n], zero4);
#pragma unroll
        for (int jj = 0; jj < 4; jj++) {
            int r = w * 16 + g * 4 + jj;
            As[0][r][swz(r, n * 16 + c)] = f2bh(fmaxf(hfr[jj] + b1N[n], 0.f));
        }
    }
    // W1/b1 for step 1
#pragma unroll
    for (int n = 0; n < 4; n++) {
        bwN[n] = zz;
        if (g == 0) bwN[n] = *(const short8*)(W1bT + (size_t)(64 + n * 16 + c) * NQ_);
        b1N[n] = b1[64 + n * 16 + c];
    }

    int cur = 0;
    for (int k0 = 0; k0 < FF_; k0 += 64, cur ^= 1) {
        int nxt = cur ^ 1;
        // write Bs[nxt] (data for step k+1)
        if (k0 + 64 < FF_) {
            *(short8*)&Bs[nxt][srow][swz(srow, scb * 8)] = preB0;
            *(short8*)&Bs[nxt][srow][swz(srow, (scb + 4) * 8)] = preB1;
        }
        // prefetch B for step k+2
        if (k0 + 128 < FF_) {
            preB0 = *(const short8*)(brow_p + k0 + 128 + scb * 8);
            preB1 = *(const short8*)(brow_p + k0 + 128 + (scb + 4) * 8);
        }
        // h-MFMA for step k+1 (pure reg; overlaps main MFMAs below)
        f32x4 hfr[4];
        if (k0 + 64 < FF_) {
#pragma unroll
            for (int n = 0; n < 4; n++) hfr[n] = mfma16(aq, bwN[n], zero4);
        }
        // main MFMAs on As[cur], Bs[cur]
#pragma unroll
        for (int kh = 0; kh < 2; kh++) {
            const short8 af = *(const short8*)&As[cur][w * 16 + c][swz(w * 16 + c, kh * 32 + g * 8)];
#pragma unroll
            for (int n = 0; n < 4; n++) {
                const short8 bfr = *(const short8*)&Bs[cur][n * 16 + c][swz(n * 16 + c, kh * 32 + g * 8)];
                acc[n] = mfma16(af, bfr, acc[n]);
            }
        }
        // relu + write h(k+1) -> As[nxt]  (wave-local rows)
        if (k0 + 64 < FF_) {
#pragma unroll
            for (int n = 0; n < 4; n++) {
#pragma unroll
                for (int jj = 0; jj < 4; jj++) {
                    int r = w * 16 + g * 4 + jj;
                    As[nxt][r][swz(r, n * 16 + c)] = f2bh(fmaxf(hfr[n][jj] + b1N[n], 0.f));
                }
            }
        }
        // W1/b1 for step k+2
        if (k0 + 128 < FF_) {
#pragma unroll
            for (int n = 0; n < 4; n++) {
                bwN[n] = zz;
                if (g == 0) bwN[n] = *(const short8*)(W1bT + (size_t)(k0 + 128 + n * 16 + c) * NQ_);
                b1N[n] = b1[k0 + 128 + n * 16 + c];
            }
        }
        __syncthreads();
    }
#pragma unroll
    for (int jj = 0; jj < 4; jj++) {
        int row = row0 + w * 16 + g * 4 + jj;
#pragma unroll
        for (int n = 0; n < 4; n++) {
            int col = col0 + n * 16 + c;
            C[(size_t)row * E_ + col] = f2bh(acc[n][jj] + b2[col]);
        }
    }
}

// ---------------------------------------------------------------------------
// Fallback GEMM2 (fused hidden via VALU) — used only if ws too small.
// ---------------------------------------------------------------------------
__global__ __launch_bounds__(256) void gemm2_fused(const float* __restrict__ xln,
                                                   const float* __restrict__ ry,
                                                   const float* __restrict__ W1,
                                                   const float* __restrict__ b1,
                                                   const float* __restrict__ W2,
                                                   const float* __restrict__ b2,
                                                   bf16* __restrict__ C) {
    __shared__ __align__(16) bf16 As[64][64];
    __shared__ __align__(16) bf16 Bst[64][64];
    __shared__ float qmS[64][NQ_];
    int row0 = blockIdx.y * 64, col0 = blockIdx.x * 64;
    int t = threadIdx.x, w = t >> 6, l = t & 63, c = l & 15, g = l >> 4;

    for (int idx = t; idx < 64 * NQ_; idx += 256) {
        int r = idx >> 3, i = idx & 7;
        qmS[r][i] = cosf(xln[(size_t)(row0 + r) * E_ + i]) * cosf(ry[i]);
    }

    f32x4 acc[4];
#pragma unroll
    for (int n = 0; n < 4; n++) acc[n] = (f32x4){0.f, 0.f, 0.f, 0.f};

    int kl = t & 63, rg = (t >> 6) * 16;
    int brow = t >> 4, bcol = (t & 15) * 4;

    for (int k0 = 0; k0 < FF_; k0 += 64) {
        __syncthreads();
        {
            float w1v[NQ_];
#pragma unroll
            for (int i = 0; i < NQ_; i++) w1v[i] = W1[i * FF_ + k0 + kl];
            float b1v = b1[k0 + kl];
#pragma unroll
            for (int r16 = 0; r16 < 16; r16++) {
                int r = rg + r16;
                float sh = b1v;
#pragma unroll
                for (int i = 0; i < NQ_; i++) sh += qmS[r][i] * w1v[i];
                As[r][swz(r, kl)] = f2bh(fmaxf(sh, 0.f));
            }
        }
#pragma unroll
        for (int it = 0; it < 4; it++) {
            int kk = brow + it * 16;
            float4 v = *(const float4*)(W2 + (size_t)(k0 + kk) * E_ + col0 + bcol);
            Bst[bcol + 0][swz(bcol + 0, kk)] = f2bh(v.x);
            Bst[bcol + 1][swz(bcol + 1, kk)] = f2bh(v.y);
            Bst[bcol + 2][swz(bcol + 2, kk)] = f2bh(v.z);
            Bst[bcol + 3][swz(bcol + 3, kk)] = f2bh(v.w);
        }
        __syncthreads();
#pragma unroll
        for (int kh = 0; kh < 2; kh++) {
            const short8 af = *(const short8*)&As[w * 16 + c][swz(w * 16 + c, kh * 32 + g * 8)];
#pragma unroll
            for (int n = 0; n < 4; n++) {
                const short8 bfr = *(const short8*)&Bst[n * 16 + c][swz(n * 16 + c, kh * 32 + g * 8)];
                acc[n] = mfma16(af, bfr, acc[n]);
            }
        }
    }
#pragma unroll
    for (int jj = 0; jj < 4; jj++) {
        int row = row0 + w * 16 + g * 4 + jj;
#pragma unroll
        for (int n = 0; n < 4; n++) {
            int col = col0 + n * 16 + c;
            C[(size_t)row * E_ + col] = f2bh(acc[n][jj] + b2[col]);
        }
    }
}

// ---------------------------------------------------------------------------
// out = LayerNorm(X + Yb) * g + be; Y in bf16.
// ---------------------------------------------------------------------------
__global__ __launch_bounds__(256) void ln_add_b(const float* __restrict__ X,
                                                const bf16* __restrict__ Yb,
                                                const float* __restrict__ g,
                                                const float* __restrict__ be,
                                                float* __restrict__ out) {
    int r = blockIdx.x;
    const size_t off = (size_t)r * E_;
    int t = threadIdx.x;
    float v[3];
    float s = 0.f, s2 = 0.f;
#pragma unroll
    for (int j = 0; j < 3; j++) {
        int e = t + j * 256;
        float val = X[off + e] + __bfloat162float(Yb[off + e]);
        v[j] = val; s += val; s2 += val * val;
    }
#pragma unroll
    for (int msk = 32; msk > 0; msk >>= 1) {
        s += __shfl_xor(s, msk);
        s2 += __shfl_xor(s2, msk);
    }
    __shared__ float red[8];
    int lane = t & 63, wv = t >> 6;
    if (lane == 0) { red[wv] = s; red[4 + wv] = s2; }
    __syncthreads();
    if (t == 0) {
        red[0] = red[0] + red[1] + red[2] + red[3];
        red[4] = red[4] + red[5] + red[6] + red[7];
    }
    __syncthreads();
    float mean = red[0] * (1.f / E_);
    float var = red[4] * (1.f / E_) - mean * mean;
    float inv = rsqrtf(var + EPS_);
#pragma unroll
    for (int j = 0; j < 3; j++) {
        int e = t + j * 256;
        out[off + e] = (v[j] - mean) * inv * g[e] + be[e];
    }
}

// ---------------------------------------------------------------------------
extern "C" void kernel_launch(void* const* d_in, const int* in_sizes, int n_in,
                              void* d_out, int out_size, void* d_ws, size_t ws_size,
                              hipStream_t stream) {
    const float* x   = (const float*)d_in[0];
    const float* W_o = (const float*)d_in[1];
    const float* b_o = (const float*)d_in[2];
    const float* g1  = (const float*)d_in[3];
    const float* be1 = (const float*)d_in[4];
    const float* g2  = (const float*)d_in[5];
    const float* be2 = (const float*)d_in[6];
    const float* ry  = (const float*)d_in[7];
    const float* W1  = (const float*)d_in[8];
    const float* b1  = (const float*)d_in[9];
    const float* W2  = (const float*)d_in[10];
    const float* b2  = (const float*)d_in[11];
    float* out = (float*)d_out;

    const size_t BSE = (size_t)B_ * S_ * E_;
    char* ws = (char*)d_ws;

    const size_t FAST_NEED = 43696128;
    bool fast = ws_size >= FAST_NEED;

    // FAST layout (bytes) — unchanged from round 9.
    bf16* xb    = (bf16*)(ws + 0);
    bf16* attnb = (bf16*)(ws + 6291456);
    bf16* WobT  = fast ? (bf16*)(ws + 12582912) : (bf16*)(ws + 18874368);
    bf16* W2bT  = (bf16*)(ws + 13762560);
    bf16* tmp1b = fast ? (bf16*)(ws + 18481152) : (bf16*)(ws + 12582912);
    float* xln  = (float*)(ws + (fast ? 24772608 : 20054016));
    bf16* W1bT  = (bf16*)(ws + 37355520);
    bf16* xT    = (bf16*)(ws + 37404672);
    bf16* tmp2b = tmp1b;

    if (fast) {
        prep_xall<<<dim3(E_ / 32, B_ * S_ / 32), 256, 0, stream>>>(x, xb, xT);
        transpose_cvt<<<dim3(E_ / 32, FF_ / 32), 256, 0, stream>>>(W2, W2bT, FF_, E_);
        prep_w1t<<<dim3(FF_ / 256), 256, 0, stream>>>(W1, W1bT);
    } else {
        prep_cvt<<<dim3((int)((BSE / 4 + 255) / 256)), 256, 0, stream>>>(x, xb, (int)(BSE / 4));
    }
    transpose_cvt<<<dim3(E_ / 32, E_ / 32), 256, 0, stream>>>(W_o, WobT, E_, E_);

    if (fast)
        attn_kernel<true><<<dim3(B_ * H_ * (S_ / 64)), 256, 0, stream>>>(xb, xT, attnb);
    else
        attn_kernel<false><<<dim3(B_ * H_ * (S_ / 64)), 256, 0, stream>>>(xb, xb, attnb);

    gemm_bf16<<<dim3(E_ / 64, (B_ * S_) / 64), 256, 0, stream>>>(
        attnb, WobT, b_o, tmp1b, B_ * S_, E_, E_);
    ln_add_b<<<dim3(B_ * S_), 256, 0, stream>>>(x, tmp1b, g1, be1, xln);

    if (fast) {
        gemm2_mfma<<<dim3(E_ / 64, (B_ * S_) / 64), 256, 0, stream>>>(
            xln, ry, W1bT, b1, W2bT, b2, tmp2b);
    } else {
        gemm2_fused<<<dim3(E_ / 64, (B_ * S_) / 64), 256, 0, stream>>>(
            xln, ry, W1, b1, W2, b2, tmp2b);
    }
    ln_add_b<<<dim3(B_ * S_), 256, 0, stream>>>(xln, tmp2b, g2, be2, out);
}

// Round 11
// 176.208 us; speedup vs baseline: 1.0567x; 1.0567x over previous
//
#include <hip/hip_runtime.h>
#include <hip/hip_bf16.h>

#define B_  2
#define S_  2048
#define E_  768
#define H_  12
#define DK_ 64
#define NQ_ 8
#define FF_ 3072
#define EPS_ 1e-5f

typedef __attribute__((ext_vector_type(8))) short short8;
typedef __attribute__((ext_vector_type(4))) float f32x4;
typedef __hip_bfloat16 bf16;

__device__ __forceinline__ bf16 f2bh(float f) { return __float2bfloat16(f); }
__device__ __forceinline__ short f2b(float f) {
    bf16 h = __float2bfloat16(f);
    return *reinterpret_cast<short*>(&h);
}

// XOR swizzle, 16B-block granular, within a 64-elem bf16 (128B) LDS row.
__device__ __forceinline__ int swz(int row, int col) {
    return (col & 7) | ((((col >> 3) ^ (row & 7)) & 7) << 3);
}

__device__ __forceinline__ f32x4 mfma16(short8 a, short8 b, f32x4 c) {
    return __builtin_amdgcn_mfma_f32_16x16x32_bf16(a, b, c, 0, 0, 0);
}

// ---------------------------------------------------------------------------
// prep: xb = bf16(x) row-major AND xT[b][e][s] transposed. One pass.
// ---------------------------------------------------------------------------
__global__ __launch_bounds__(256) void prep_xall(const float* __restrict__ x,
                                                 bf16* __restrict__ xb,
                                                 bf16* __restrict__ xT) {
    __shared__ float tile[32][33];
    int e0 = blockIdx.x * 32, s0 = blockIdx.y * 32;
    int tx = threadIdx.x & 31, ty = threadIdx.x >> 5;
    int b = s0 >> 11, sl0 = s0 & 2047;
#pragma unroll
    for (int i = 0; i < 4; i++) {
        int row = ty + i * 8;
        float v = x[(size_t)(s0 + row) * E_ + e0 + tx];
        tile[row][tx] = v;
        xb[(size_t)(s0 + row) * E_ + e0 + tx] = f2bh(v);
    }
    __syncthreads();
#pragma unroll
    for (int i = 0; i < 4; i++) {
        int row = ty + i * 8;
        xT[((size_t)b * E_ + e0 + row) * S_ + sl0 + tx] = f2bh(tile[tx][row]);
    }
}

// ---------------------------------------------------------------------------
// prep: xb = bf16(x)  (fallback path only)
// ---------------------------------------------------------------------------
__global__ __launch_bounds__(256) void prep_cvt(const float* __restrict__ x,
                                                bf16* __restrict__ xb, int n4) {
    int i = blockIdx.x * 256 + threadIdx.x;
    if (i >= n4) return;
    float4 f = *(const float4*)(x + (size_t)i * 4);
    short4 sv;
    sv.x = f2b(f.x); sv.y = f2b(f.y); sv.z = f2b(f.z); sv.w = f2b(f.w);
    *(short4*)((short*)xb + (size_t)i * 4) = sv;
}

// ---------------------------------------------------------------------------
// prep: WT[N][K] = bf16(W[K][N])
// ---------------------------------------------------------------------------
__global__ __launch_bounds__(256) void transpose_cvt(const float* __restrict__ W,
                                                     bf16* __restrict__ WT,
                                                     int K, int N) {
    __shared__ float tile[32][33];
    int k0 = blockIdx.y * 32, n0 = blockIdx.x * 32;
    int tx = threadIdx.x & 31, ty = threadIdx.x >> 5;
#pragma unroll
    for (int i = 0; i < 4; i++) {
        int row = ty + i * 8;
        tile[row][tx] = W[(size_t)(k0 + row) * N + n0 + tx];
    }
    __syncthreads();
#pragma unroll
    for (int i = 0; i < 4; i++) {
        int row = ty + i * 8;
        WT[(size_t)(n0 + row) * K + k0 + tx] = f2bh(tile[tx][row]);
    }
}

// ---------------------------------------------------------------------------
// prep: W1bT[k][i] = bf16(W1[i][k])
// ---------------------------------------------------------------------------
__global__ __launch_bounds__(256) void prep_w1t(const float* __restrict__ W1,
                                                bf16* __restrict__ W1bT) {
    int k = blockIdx.x * 256 + threadIdx.x;
    if (k >= FF_) return;
    short8 v;
#pragma unroll
    for (int i = 0; i < NQ_; i++) v[i] = f2b(W1[(size_t)i * FF_ + k]);
    *(short8*)(W1bT + (size_t)k * NQ_) = v;
}

// ---------------------------------------------------------------------------
// MFMA flash attention, no-max softmax, DOUBLE-BUFFERED K/V (one barrier
// per K-tile — same hazard proof as gemm_bf16's dbuf), reg-prefetch,
// XCD-chunked swizzle, setprio on MFMA clusters.
// ---------------------------------------------------------------------------
template<bool XT>
__global__ __launch_bounds__(256) void attn_kernel(const bf16* __restrict__ xb,
                                                   const bf16* __restrict__ xT,
                                                   bf16* __restrict__ out) {
    const int qtiles = S_ / 64;                  // 32
    const int nwg = B_ * H_ * qtiles;            // 768
    int o = blockIdx.x;
    int blk = (o & 7) * (nwg >> 3) + (o >> 3);
    int qt = blk % qtiles;
    int hh = (blk / qtiles) % H_;
    int bb = blk / (qtiles * H_);
    const bf16* base = xb + (size_t)bb * S_ * E_ + hh * DK_;
    const bf16* baseT = xT + ((size_t)bb * E_ + hh * DK_) * S_;

    __shared__ __align__(16) bf16 Ks[2][64][64];     // [key][d]  swizzled
    __shared__ __align__(16) bf16 Vt[2][64][64];     // [d][key]  swizzled
    __shared__ __align__(16) bf16 Pl[4][16][64];     // per-wave P [q][key]

    int t = threadIdx.x;
    int w = t >> 6, l = t & 63, c = l & 15, g = l >> 4;

    short8 qf[2];
    {
        const bf16* qp = base + (size_t)(qt * 64 + w * 16 + c) * E_;
        qf[0] = *(const short8*)(qp + g * 8);
        qf[1] = *(const short8*)(qp + 32 + g * 8);
    }

    f32x4 oacc[4];
    float l_part[4];
#pragma unroll
    for (int n = 0; n < 4; n++) { oacc[n] = (f32x4){0.f, 0.f, 0.f, 0.f}; l_part[n] = 0.f; }

    int skey = t & 63;
    int scb0 = t >> 6;

    // prologue: tile 0 -> buf0; prefetch tile 1 into regs
    short8 preK[2], preV[2];
#pragma unroll
    for (int it = 0; it < 2; it++) {
        preK[it] = *(const short8*)(base + (size_t)skey * E_ + (scb0 + it * 4) * 8);
        if (XT)
            preV[it] = *(const short8*)(baseT + (size_t)skey * S_ + (scb0 + it * 4) * 8);
    }
#pragma unroll
    for (int it = 0; it < 2; it++) {
        int cb = scb0 + it * 4;
        *(short8*)&Ks[0][skey][swz(skey, cb * 8)] = preK[it];
        if (XT) {
            *(short8*)&Vt[0][skey][swz(skey, cb * 8)] = preV[it];
        } else {
#pragma unroll
            for (int j = 0; j < 8; j++) {
                int d = cb * 8 + j;
                short sv = preK[it][j];
                Vt[0][d][swz(d, skey)] = *reinterpret_cast<bf16*>(&sv);
            }
        }
    }
#pragma unroll
    for (int it = 0; it < 2; it++) {
        preK[it] = *(const short8*)(base + (size_t)(64 + skey) * E_ + (scb0 + it * 4) * 8);
        if (XT)
            preV[it] = *(const short8*)(baseT + (size_t)skey * S_ + 64 + (scb0 + it * 4) * 8);
    }
    __syncthreads();

    int cur = 0;
    for (int kt = 0; kt < S_ / 64; kt++, cur ^= 1) {
        int nxt = cur ^ 1;
        // write next tile from prefetched regs (overlaps MFMA below)
        if (kt + 1 < S_ / 64) {
#pragma unroll
            for (int it = 0; it < 2; it++) {
                int cb = scb0 + it * 4;
                *(short8*)&Ks[nxt][skey][swz(skey, cb * 8)] = preK[it];
                if (XT) {
                    *(short8*)&Vt[nxt][skey][swz(skey, cb * 8)] = preV[it];
                } else {
#pragma unroll
                    for (int j = 0; j < 8; j++) {
                        int d = cb * 8 + j;
                        short sv = preK[it][j];
                        Vt[nxt][d][swz(d, skey)] = *reinterpret_cast<bf16*>(&sv);
                    }
                }
            }
        }
        // prefetch tile kt+2
        if (kt + 2 < S_ / 64) {
#pragma unroll
            for (int it = 0; it < 2; it++) {
                preK[it] = *(const short8*)(base + (size_t)((kt + 2) * 64 + skey) * E_ + (scb0 + it * 4) * 8);
                if (XT)
                    preV[it] = *(const short8*)(baseT + (size_t)skey * S_ + (kt + 2) * 64 + (scb0 + it * 4) * 8);
            }
        }

        // S = Q K^T on buf[cur]
        f32x4 sfr[4];
        __builtin_amdgcn_s_setprio(1);
#pragma unroll
        for (int n = 0; n < 4; n++) {
            sfr[n] = (f32x4){0.f, 0.f, 0.f, 0.f};
#pragma unroll
            for (int kh = 0; kh < 2; kh++) {
                const short8 bfr = *(const short8*)&Ks[cur][n * 16 + c][swz(n * 16 + c, kh * 32 + g * 8)];
                sfr[n] = mfma16(qf[kh], bfr, sfr[n]);
            }
        }
        __builtin_amdgcn_s_setprio(0);
#pragma unroll
        for (int jj = 0; jj < 4; jj++) {
            float pv[4];
#pragma unroll
            for (int n = 0; n < 4; n++)
                pv[n] = exp2f(sfr[n][jj] * 0.18033688f);   // log2(e)/8
            l_part[jj] += (pv[0] + pv[1]) + (pv[2] + pv[3]);
            int r = g * 4 + jj;
#pragma unroll
            for (int n = 0; n < 4; n++)
                Pl[w][r][swz(r, n * 16 + c)] = f2bh(pv[n]);
        }

        __builtin_amdgcn_s_setprio(1);
#pragma unroll
        for (int ks = 0; ks < 2; ks++) {
            short8 vb[4];
#pragma unroll
            for (int dn = 0; dn < 4; dn++)
                vb[dn] = *(const short8*)&Vt[cur][dn * 16 + c][swz(dn * 16 + c, ks * 32 + g * 8)];
            const short8 pa = *(const short8*)&Pl[w][c][swz(c, ks * 32 + g * 8)];
#pragma unroll
            for (int dn = 0; dn < 4; dn++)
                oacc[dn] = mfma16(pa, vb[dn], oacc[dn]);
        }
        __builtin_amdgcn_s_setprio(0);
        __syncthreads();
    }

#pragma unroll
    for (int jj = 0; jj < 4; jj++) {
        float lv = l_part[jj];
#pragma unroll
        for (int msk = 1; msk < 16; msk <<= 1) lv += __shfl_xor(lv, msk);
        float inv = 1.f / lv;
        size_t ro = ((size_t)bb * S_ + qt * 64 + w * 16 + g * 4 + jj) * E_ + hh * DK_;
#pragma unroll
        for (int dn = 0; dn < 4; dn++)
            out[ro + dn * 16 + c] = f2bh(oacc[dn][jj] * inv);
    }
}

// ---------------------------------------------------------------------------
// bf16 GEMM (unchanged — known good).
// ---------------------------------------------------------------------------
__global__ __launch_bounds__(256) void gemm_bf16(const bf16* __restrict__ A,
                                                 const bf16* __restrict__ BT,
                                                 const float* __restrict__ bias,
                                                 bf16* __restrict__ C,
                                                 int M, int N, int K) {
    __shared__ __align__(16) bf16 As2[2][64][64];
    __shared__ __align__(16) bf16 Bs2[2][64][64];
    int nbx = gridDim.x, nwg = nbx * gridDim.y;
    int id = blockIdx.y * nbx + blockIdx.x;
    int id2 = (nwg & 7) ? id : ((id & 7) * (nwg >> 3) + (id >> 3));
    int row0 = (id2 / nbx) * 64, col0 = (id2 % nbx) * 64;
    int t = threadIdx.x, w = t >> 6, l = t & 63, c = l & 15, g = l >> 4;

    f32x4 acc[4];
#pragma unroll
    for (int n = 0; n < 4; n++) acc[n] = (f32x4){0.f, 0.f, 0.f, 0.f};

    int srow = t & 63, scb = t >> 6;
    const bf16* ap = A + (size_t)(row0 + srow) * K;
    const bf16* bp = BT + (size_t)(col0 + srow) * K;

    short8 pA0, pA1, pB0, pB1;
    pA0 = *(const short8*)(ap + scb * 8);
    pA1 = *(const short8*)(ap + (scb + 4) * 8);
    pB0 = *(const short8*)(bp + scb * 8);
    pB1 = *(const short8*)(bp + (scb + 4) * 8);
    *(short8*)&As2[0][srow][swz(srow, scb * 8)] = pA0;
    *(short8*)&As2[0][srow][swz(srow, (scb + 4) * 8)] = pA1;
    *(short8*)&Bs2[0][srow][swz(srow, scb * 8)] = pB0;
    *(short8*)&Bs2[0][srow][swz(srow, (scb + 4) * 8)] = pB1;
    if (64 < K) {
        pA0 = *(const short8*)(ap + 64 + scb * 8);
        pA1 = *(const short8*)(ap + 64 + (scb + 4) * 8);
        pB0 = *(const short8*)(bp + 64 + scb * 8);
        pB1 = *(const short8*)(bp + 64 + (scb + 4) * 8);
    }
    __syncthreads();

    int cur = 0;
    for (int k0 = 0; k0 < K; k0 += 64, cur ^= 1) {
        int nxt = cur ^ 1;
        if (k0 + 64 < K) {
            *(short8*)&As2[nxt][srow][swz(srow, scb * 8)] = pA0;
            *(short8*)&As2[nxt][srow][swz(srow, (scb + 4) * 8)] = pA1;
            *(short8*)&Bs2[nxt][srow][swz(srow, scb * 8)] = pB0;
            *(short8*)&Bs2[nxt][srow][swz(srow, (scb + 4) * 8)] = pB1;
        }
        if (k0 + 128 < K) {
            pA0 = *(const short8*)(ap + k0 + 128 + scb * 8);
            pA1 = *(const short8*)(ap + k0 + 128 + (scb + 4) * 8);
            pB0 = *(const short8*)(bp + k0 + 128 + scb * 8);
            pB1 = *(const short8*)(bp + k0 + 128 + (scb + 4) * 8);
        }
#pragma unroll
        for (int kh = 0; kh < 2; kh++) {
            const short8 af = *(const short8*)&As2[cur][w * 16 + c][swz(w * 16 + c, kh * 32 + g * 8)];
#pragma unroll
            for (int n = 0; n < 4; n++) {
                const short8 bfr = *(const short8*)&Bs2[cur][n * 16 + c][swz(n * 16 + c, kh * 32 + g * 8)];
                acc[n] = mfma16(af, bfr, acc[n]);
            }
        }
        __syncthreads();
    }
#pragma unroll
    for (int jj = 0; jj < 4; jj++) {
        int row = row0 + w * 16 + g * 4 + jj;
#pragma unroll
        for (int n = 0; n < 4; n++) {
            int col = col0 + n * 16 + c;
            C[(size_t)row * N + col] = f2bh(acc[n][jj] + bias[col]);
        }
    }
}

// ---------------------------------------------------------------------------
// GEMM2 with in-kernel h via MFMA, double-buffered Bs/W1t, single barrier
// per K-step. (REVERTED to round-9 version — round-10 h-pipeline regressed.)
// ---------------------------------------------------------------------------
__global__ __launch_bounds__(256) void gemm2_mfma(const float* __restrict__ xln,
                                                  const float* __restrict__ ry,
                                                  const bf16* __restrict__ W1bT,
                                                  const float* __restrict__ b1,
                                                  const bf16* __restrict__ W2bT,
                                                  const float* __restrict__ b2,
                                                  bf16* __restrict__ C) {
    __shared__ __align__(16) bf16 As[64][64];
    __shared__ __align__(16) bf16 Bs[2][64][64];
    __shared__ __align__(16) bf16 W1t[2][64][8];
    __shared__ __align__(16) bf16 qm_s[64][8];
    const int nbx = E_ / 64;                    // 12
    const int nwg = nbx * (B_ * S_ / 64);       // 768
    int id = blockIdx.y * nbx + blockIdx.x;
    int id2 = (id & 7) * (nwg >> 3) + (id >> 3);
    int row0 = (id2 / nbx) * 64, col0 = (id2 % nbx) * 64;
    int t = threadIdx.x, w = t >> 6, l = t & 63, c = l & 15, g = l >> 4;

    if (t < 64) {
        const float* xp = xln + (size_t)(row0 + t) * E_;
#pragma unroll
        for (int i = 0; i < NQ_; i++)
            qm_s[t][i] = f2bh(cosf(xp[i]) * cosf(ry[i]));
    }

    f32x4 acc[4];
#pragma unroll
    for (int n = 0; n < 4; n++) acc[n] = (f32x4){0.f, 0.f, 0.f, 0.f};

    int srow = t & 63, scb = t >> 6;
    const bf16* brow_p = W2bT + (size_t)(col0 + srow) * FF_;

    short8 preB0, preB1, preW;
    preB0 = *(const short8*)(brow_p + scb * 8);
    preB1 = *(const short8*)(brow_p + (scb + 4) * 8);
    if (t < 64) preW = *(const short8*)(W1bT + (size_t)t * NQ_);
    *(short8*)&Bs[0][srow][swz(srow, scb * 8)] = preB0;
    *(short8*)&Bs[0][srow][swz(srow, (scb + 4) * 8)] = preB1;
    if (t < 64) *(short8*)&W1t[0][t][0] = preW;
    preB0 = *(const short8*)(brow_p + 64 + scb * 8);
    preB1 = *(const short8*)(brow_p + 64 + (scb + 4) * 8);
    if (t < 64) preW = *(const short8*)(W1bT + (size_t)(64 + t) * NQ_);
    __syncthreads();

    short8 zz = {0, 0, 0, 0, 0, 0, 0, 0};
    short8 aq = zz;
    if (g == 0) aq = *(const short8*)&qm_s[w * 16 + c][0];

    int cur = 0;
    for (int k0 = 0; k0 < FF_; k0 += 64, cur ^= 1) {
        float b1c[4];
#pragma unroll
        for (int n = 0; n < 4; n++) b1c[n] = b1[k0 + n * 16 + c];

        int nxt = cur ^ 1;
        if (k0 + 64 < FF_) {
            *(short8*)&Bs[nxt][srow][swz(srow, scb * 8)] = preB0;
            *(short8*)&Bs[nxt][srow][swz(srow, (scb + 4) * 8)] = preB1;
            if (t < 64) *(short8*)&W1t[nxt][t][0] = preW;
        }
        if (k0 + 128 < FF_) {
            preB0 = *(const short8*)(brow_p + k0 + 128 + scb * 8);
            preB1 = *(const short8*)(brow_p + k0 + 128 + (scb + 4) * 8);
            if (t < 64) preW = *(const short8*)(W1bT + (size_t)(k0 + 128 + t) * NQ_);
        }

        f32x4 zero4 = {0.f, 0.f, 0.f, 0.f};
#pragma unroll
        for (int n = 0; n < 4; n++) {
            short8 bw = zz;
            if (g == 0) bw = *(const short8*)&W1t[cur][n * 16 + c][0];
            f32x4 hfr = mfma16(aq, bw, zero4);
#pragma unroll
            for (int jj = 0; jj < 4; jj++) {
                float hv = fmaxf(hfr[jj] + b1c[n], 0.f);
                int r = w * 16 + g * 4 + jj;
                As[r][swz(r, n * 16 + c)] = f2bh(hv);
            }
        }

#pragma unroll
        for (int kh = 0; kh < 2; kh++) {
            const short8 af = *(const short8*)&As[w * 16 + c][swz(w * 16 + c, kh * 32 + g * 8)];
#pragma unroll
            for (int n = 0; n < 4; n++) {
                const short8 bfr = *(const short8*)&Bs[cur][n * 16 + c][swz(n * 16 + c, kh * 32 + g * 8)];
                acc[n] = mfma16(af, bfr, acc[n]);
            }
        }
        __syncthreads();
    }
#pragma unroll
    for (int jj = 0; jj < 4; jj++) {
        int row = row0 + w * 16 + g * 4 + jj;
#pragma unroll
        for (int n = 0; n < 4; n++) {
            int col = col0 + n * 16 + c;
            C[(size_t)row * E_ + col] = f2bh(acc[n][jj] + b2[col]);
        }
    }
}

// ---------------------------------------------------------------------------
// Fallback GEMM2 (fused hidden via VALU) — used only if ws too small.
// ---------------------------------------------------------------------------
__global__ __launch_bounds__(256) void gemm2_fused(const float* __restrict__ xln,
                                                   const float* __restrict__ ry,
                                                   const float* __restrict__ W1,
                                                   const float* __restrict__ b1,
                                                   const float* __restrict__ W2,
                                                   const float* __restrict__ b2,
                                                   bf16* __restrict__ C) {
    __shared__ __align__(16) bf16 As[64][64];
    __shared__ __align__(16) bf16 Bst[64][64];
    __shared__ float qmS[64][NQ_];
    int row0 = blockIdx.y * 64, col0 = blockIdx.x * 64;
    int t = threadIdx.x, w = t >> 6, l = t & 63, c = l & 15, g = l >> 4;

    for (int idx = t; idx < 64 * NQ_; idx += 256) {
        int r = idx >> 3, i = idx & 7;
        qmS[r][i] = cosf(xln[(size_t)(row0 + r) * E_ + i]) * cosf(ry[i]);
    }

    f32x4 acc[4];
#pragma unroll
    for (int n = 0; n < 4; n++) acc[n] = (f32x4){0.f, 0.f, 0.f, 0.f};

    int kl = t & 63, rg = (t >> 6) * 16;
    int brow = t >> 4, bcol = (t & 15) * 4;

    for (int k0 = 0; k0 < FF_; k0 += 64) {
        __syncthreads();
        {
            float w1v[NQ_];
#pragma unroll
            for (int i = 0; i < NQ_; i++) w1v[i] = W1[i * FF_ + k0 + kl];
            float b1v = b1[k0 + kl];
#pragma unroll
            for (int r16 = 0; r16 < 16; r16++) {
                int r = rg + r16;
                float sh = b1v;
#pragma unroll
                for (int i = 0; i < NQ_; i++) sh += qmS[r][i] * w1v[i];
                As[r][swz(r, kl)] = f2bh(fmaxf(sh, 0.f));
            }
        }
#pragma unroll
        for (int it = 0; it < 4; it++) {
            int kk = brow + it * 16;
            float4 v = *(const float4*)(W2 + (size_t)(k0 + kk) * E_ + col0 + bcol);
            Bst[bcol + 0][swz(bcol + 0, kk)] = f2bh(v.x);
            Bst[bcol + 1][swz(bcol + 1, kk)] = f2bh(v.y);
            Bst[bcol + 2][swz(bcol + 2, kk)] = f2bh(v.z);
            Bst[bcol + 3][swz(bcol + 3, kk)] = f2bh(v.w);
        }
        __syncthreads();
#pragma unroll
        for (int kh = 0; kh < 2; kh++) {
            const short8 af = *(const short8*)&As[w * 16 + c][swz(w * 16 + c, kh * 32 + g * 8)];
#pragma unroll
            for (int n = 0; n < 4; n++) {
                const short8 bfr = *(const short8*)&Bst[n * 16 + c][swz(n * 16 + c, kh * 32 + g * 8)];
                acc[n] = mfma16(af, bfr, acc[n]);
            }
        }
    }
#pragma unroll
    for (int jj = 0; jj < 4; jj++) {
        int row = row0 + w * 16 + g * 4 + jj;
#pragma unroll
        for (int n = 0; n < 4; n++) {
            int col = col0 + n * 16 + c;
            C[(size_t)row * E_ + col] = f2bh(acc[n][jj] + b2[col]);
        }
    }
}

// ---------------------------------------------------------------------------
// out = LayerNorm(X + Yb) * g + be; Y in bf16.
// ---------------------------------------------------------------------------
__global__ __launch_bounds__(256) void ln_add_b(const float* __restrict__ X,
                                                const bf16* __restrict__ Yb,
                                                const float* __restrict__ g,
                                                const float* __restrict__ be,
                                                float* __restrict__ out) {
    int r = blockIdx.x;
    const size_t off = (size_t)r * E_;
    int t = threadIdx.x;
    float v[3];
    float s = 0.f, s2 = 0.f;
#pragma unroll
    for (int j = 0; j < 3; j++) {
        int e = t + j * 256;
        float val = X[off + e] + __bfloat162float(Yb[off + e]);
        v[j] = val; s += val; s2 += val * val;
    }
#pragma unroll
    for (int msk = 32; msk > 0; msk >>= 1) {
        s += __shfl_xor(s, msk);
        s2 += __shfl_xor(s2, msk);
    }
    __shared__ float red[8];
    int lane = t & 63, wv = t >> 6;
    if (lane == 0) { red[wv] = s; red[4 + wv] = s2; }
    __syncthreads();
    if (t == 0) {
        red[0] = red[0] + red[1] + red[2] + red[3];
        red[4] = red[4] + red[5] + red[6] + red[7];
    }
    __syncthreads();
    float mean = red[0] * (1.f / E_);
    float var = red[4] * (1.f / E_) - mean * mean;
    float inv = rsqrtf(var + EPS_);
#pragma unroll
    for (int j = 0; j < 3; j++) {
        int e = t + j * 256;
        out[off + e] = (v[j] - mean) * inv * g[e] + be[e];
    }
}

// ---------------------------------------------------------------------------
extern "C" void kernel_launch(void* const* d_in, const int* in_sizes, int n_in,
                              void* d_out, int out_size, void* d_ws, size_t ws_size,
                              hipStream_t stream) {
    const float* x   = (const float*)d_in[0];
    const float* W_o = (const float*)d_in[1];
    const float* b_o = (const float*)d_in[2];
    const float* g1  = (const float*)d_in[3];
    const float* be1 = (const float*)d_in[4];
    const float* g2  = (const float*)d_in[5];
    const float* be2 = (const float*)d_in[6];
    const float* ry  = (const float*)d_in[7];
    const float* W1  = (const float*)d_in[8];
    const float* b1  = (const float*)d_in[9];
    const float* W2  = (const float*)d_in[10];
    const float* b2  = (const float*)d_in[11];
    float* out = (float*)d_out;

    const size_t BSE = (size_t)B_ * S_ * E_;
    char* ws = (char*)d_ws;

    const size_t FAST_NEED = 43696128;
    bool fast = ws_size >= FAST_NEED;

    // FAST layout (bytes) — unchanged from round 9.
    bf16* xb    = (bf16*)(ws + 0);
    bf16* attnb = (bf16*)(ws + 6291456);
    bf16* WobT  = fast ? (bf16*)(ws + 12582912) : (bf16*)(ws + 18874368);
    bf16* W2bT  = (bf16*)(ws + 13762560);
    bf16* tmp1b = fast ? (bf16*)(ws + 18481152) : (bf16*)(ws + 12582912);
    float* xln  = (float*)(ws + (fast ? 24772608 : 20054016));
    bf16* W1bT  = (bf16*)(ws + 37355520);
    bf16* xT    = (bf16*)(ws + 37404672);
    bf16* tmp2b = tmp1b;

    if (fast) {
        prep_xall<<<dim3(E_ / 32, B_ * S_ / 32), 256, 0, stream>>>(x, xb, xT);
        transpose_cvt<<<dim3(E_ / 32, FF_ / 32), 256, 0, stream>>>(W2, W2bT, FF_, E_);
        prep_w1t<<<dim3(FF_ / 256), 256, 0, stream>>>(W1, W1bT);
    } else {
        prep_cvt<<<dim3((int)((BSE / 4 + 255) / 256)), 256, 0, stream>>>(x, xb, (int)(BSE / 4));
    }
    transpose_cvt<<<dim3(E_ / 32, E_ / 32), 256, 0, stream>>>(W_o, WobT, E_, E_);

    if (fast)
        attn_kernel<true><<<dim3(B_ * H_ * (S_ / 64)), 256, 0, stream>>>(xb, xT, attnb);
    else
        attn_kernel<false><<<dim3(B_ * H_ * (S_ / 64)), 256, 0, stream>>>(xb, xb, attnb);

    gemm_bf16<<<dim3(E_ / 64, (B_ * S_) / 64), 256, 0, stream>>>(
        attnb, WobT, b_o, tmp1b, B_ * S_, E_, E_);
    ln_add_b<<<dim3(B_ * S_), 256, 0, stream>>>(x, tmp1b, g1, be1, xln);

    if (fast) {
        gemm2_mfma<<<dim3(E_ / 64, (B_ * S_) / 64), 256, 0, stream>>>(
            xln, ry, W1bT, b1, W2bT, b2, tmp2b);
    } else {
        gemm2_fused<<<dim3(E_ / 64, (B_ * S_) / 64), 256, 0, stream>>>(
            xln, ry, W1, b1, W2, b2, tmp2b);
    }
    ln_add_b<<<dim3(B_ * S_), 256, 0, stream>>>(xln, tmp2b, g2, be2, out);
}

// Round 12
// 164.267 us; speedup vs baseline: 1.1335x; 1.0727x over previous
//
#include <hip/hip_runtime.h>
#include <hip/hip_bf16.h>

#define B_  2
#define S_  2048
#define E_  768
#define H_  12
#define DK_ 64
#define NQ_ 8
#define FF_ 3072
#define EPS_ 1e-5f

typedef __attribute__((ext_vector_type(8))) short short8;
typedef __attribute__((ext_vector_type(4))) float f32x4;
typedef __hip_bfloat16 bf16;

__device__ __forceinline__ bf16 f2bh(float f) { return __float2bfloat16(f); }
__device__ __forceinline__ short f2b(float f) {
    bf16 h = __float2bfloat16(f);
    return *reinterpret_cast<short*>(&h);
}

// XOR swizzle, 16B-block granular, within a 64-elem bf16 (128B) LDS row.
__device__ __forceinline__ int swz(int row, int col) {
    return (col & 7) | ((((col >> 3) ^ (row & 7)) & 7) << 3);
}

__device__ __forceinline__ f32x4 mfma16(short8 a, short8 b, f32x4 c) {
    return __builtin_amdgcn_mfma_f32_16x16x32_bf16(a, b, c, 0, 0, 0);
}

// Async global->LDS, 16B per lane. LDS dest: wave-uniform base + lane*16.
// Global src is per-lane (pre-inverse-swizzled so swz() reads stay correct).
__device__ __forceinline__ void gload16(const bf16* g, bf16* l) {
    __builtin_amdgcn_global_load_lds(
        (__attribute__((address_space(1))) void*)g,
        (__attribute__((address_space(3))) void*)l, 16, 0, 0);
}

// ---------------------------------------------------------------------------
// prep: xb = bf16(x) row-major AND xT[b][e][s] transposed. One pass.
// ---------------------------------------------------------------------------
__global__ __launch_bounds__(256) void prep_xall(const float* __restrict__ x,
                                                 bf16* __restrict__ xb,
                                                 bf16* __restrict__ xT) {
    __shared__ float tile[32][33];
    int e0 = blockIdx.x * 32, s0 = blockIdx.y * 32;
    int tx = threadIdx.x & 31, ty = threadIdx.x >> 5;
    int b = s0 >> 11, sl0 = s0 & 2047;
#pragma unroll
    for (int i = 0; i < 4; i++) {
        int row = ty + i * 8;
        float v = x[(size_t)(s0 + row) * E_ + e0 + tx];
        tile[row][tx] = v;
        xb[(size_t)(s0 + row) * E_ + e0 + tx] = f2bh(v);
    }
    __syncthreads();
#pragma unroll
    for (int i = 0; i < 4; i++) {
        int row = ty + i * 8;
        xT[((size_t)b * E_ + e0 + row) * S_ + sl0 + tx] = f2bh(tile[tx][row]);
    }
}

// ---------------------------------------------------------------------------
// prep: xb = bf16(x)  (fallback path only)
// ---------------------------------------------------------------------------
__global__ __launch_bounds__(256) void prep_cvt(const float* __restrict__ x,
                                                bf16* __restrict__ xb, int n4) {
    int i = blockIdx.x * 256 + threadIdx.x;
    if (i >= n4) return;
    float4 f = *(const float4*)(x + (size_t)i * 4);
    short4 sv;
    sv.x = f2b(f.x); sv.y = f2b(f.y); sv.z = f2b(f.z); sv.w = f2b(f.w);
    *(short4*)((short*)xb + (size_t)i * 4) = sv;
}

// ---------------------------------------------------------------------------
// prep: WT[N][K] = bf16(W[K][N])
// ---------------------------------------------------------------------------
__global__ __launch_bounds__(256) void transpose_cvt(const float* __restrict__ W,
                                                     bf16* __restrict__ WT,
                                                     int K, int N) {
    __shared__ float tile[32][33];
    int k0 = blockIdx.y * 32, n0 = blockIdx.x * 32;
    int tx = threadIdx.x & 31, ty = threadIdx.x >> 5;
#pragma unroll
    for (int i = 0; i < 4; i++) {
        int row = ty + i * 8;
        tile[row][tx] = W[(size_t)(k0 + row) * N + n0 + tx];
    }
    __syncthreads();
#pragma unroll
    for (int i = 0; i < 4; i++) {
        int row = ty + i * 8;
        WT[(size_t)(n0 + row) * K + k0 + tx] = f2bh(tile[tx][row]);
    }
}

// ---------------------------------------------------------------------------
// prep: W1bT[k][i] = bf16(W1[i][k])
// ---------------------------------------------------------------------------
__global__ __launch_bounds__(256) void prep_w1t(const float* __restrict__ W1,
                                                bf16* __restrict__ W1bT) {
    int k = blockIdx.x * 256 + threadIdx.x;
    if (k >= FF_) return;
    short8 v;
#pragma unroll
    for (int i = 0; i < NQ_; i++) v[i] = f2b(W1[(size_t)i * FF_ + k]);
    *(short8*)(W1bT + (size_t)k * NQ_) = v;
}

// ---------------------------------------------------------------------------
// MFMA flash attention (unchanged from round 11).
// ---------------------------------------------------------------------------
template<bool XT>
__global__ __launch_bounds__(256) void attn_kernel(const bf16* __restrict__ xb,
                                                   const bf16* __restrict__ xT,
                                                   bf16* __restrict__ out) {
    const int qtiles = S_ / 64;                  // 32
    const int nwg = B_ * H_ * qtiles;            // 768
    int o = blockIdx.x;
    int blk = (o & 7) * (nwg >> 3) + (o >> 3);
    int qt = blk % qtiles;
    int hh = (blk / qtiles) % H_;
    int bb = blk / (qtiles * H_);
    const bf16* base = xb + (size_t)bb * S_ * E_ + hh * DK_;
    const bf16* baseT = xT + ((size_t)bb * E_ + hh * DK_) * S_;

    __shared__ __align__(16) bf16 Ks[2][64][64];
    __shared__ __align__(16) bf16 Vt[2][64][64];
    __shared__ __align__(16) bf16 Pl[4][16][64];

    int t = threadIdx.x;
    int w = t >> 6, l = t & 63, c = l & 15, g = l >> 4;

    short8 qf[2];
    {
        const bf16* qp = base + (size_t)(qt * 64 + w * 16 + c) * E_;
        qf[0] = *(const short8*)(qp + g * 8);
        qf[1] = *(const short8*)(qp + 32 + g * 8);
    }

    f32x4 oacc[4];
    float l_part[4];
#pragma unroll
    for (int n = 0; n < 4; n++) { oacc[n] = (f32x4){0.f, 0.f, 0.f, 0.f}; l_part[n] = 0.f; }

    int skey = t & 63;
    int scb0 = t >> 6;

    short8 preK[2], preV[2];
#pragma unroll
    for (int it = 0; it < 2; it++) {
        preK[it] = *(const short8*)(base + (size_t)skey * E_ + (scb0 + it * 4) * 8);
        if (XT)
            preV[it] = *(const short8*)(baseT + (size_t)skey * S_ + (scb0 + it * 4) * 8);
    }
#pragma unroll
    for (int it = 0; it < 2; it++) {
        int cb = scb0 + it * 4;
        *(short8*)&Ks[0][skey][swz(skey, cb * 8)] = preK[it];
        if (XT) {
            *(short8*)&Vt[0][skey][swz(skey, cb * 8)] = preV[it];
        } else {
#pragma unroll
            for (int j = 0; j < 8; j++) {
                int d = cb * 8 + j;
                short sv = preK[it][j];
                Vt[0][d][swz(d, skey)] = *reinterpret_cast<bf16*>(&sv);
            }
        }
    }
#pragma unroll
    for (int it = 0; it < 2; it++) {
        preK[it] = *(const short8*)(base + (size_t)(64 + skey) * E_ + (scb0 + it * 4) * 8);
        if (XT)
            preV[it] = *(const short8*)(baseT + (size_t)skey * S_ + 64 + (scb0 + it * 4) * 8);
    }
    __syncthreads();

    int cur = 0;
    for (int kt = 0; kt < S_ / 64; kt++, cur ^= 1) {
        int nxt = cur ^ 1;
        if (kt + 1 < S_ / 64) {
#pragma unroll
            for (int it = 0; it < 2; it++) {
                int cb = scb0 + it * 4;
                *(short8*)&Ks[nxt][skey][swz(skey, cb * 8)] = preK[it];
                if (XT) {
                    *(short8*)&Vt[nxt][skey][swz(skey, cb * 8)] = preV[it];
                } else {
#pragma unroll
                    for (int j = 0; j < 8; j++) {
                        int d = cb * 8 + j;
                        short sv = preK[it][j];
                        Vt[nxt][d][swz(d, skey)] = *reinterpret_cast<bf16*>(&sv);
                    }
                }
            }
        }
        if (kt + 2 < S_ / 64) {
#pragma unroll
            for (int it = 0; it < 2; it++) {
                preK[it] = *(const short8*)(base + (size_t)((kt + 2) * 64 + skey) * E_ + (scb0 + it * 4) * 8);
                if (XT)
                    preV[it] = *(const short8*)(baseT + (size_t)skey * S_ + (kt + 2) * 64 + (scb0 + it * 4) * 8);
            }
        }

        f32x4 sfr[4];
        __builtin_amdgcn_s_setprio(1);
#pragma unroll
        for (int n = 0; n < 4; n++) {
            sfr[n] = (f32x4){0.f, 0.f, 0.f, 0.f};
#pragma unroll
            for (int kh = 0; kh < 2; kh++) {
                const short8 bfr = *(const short8*)&Ks[cur][n * 16 + c][swz(n * 16 + c, kh * 32 + g * 8)];
                sfr[n] = mfma16(qf[kh], bfr, sfr[n]);
            }
        }
        __builtin_amdgcn_s_setprio(0);
#pragma unroll
        for (int jj = 0; jj < 4; jj++) {
            float pv[4];
#pragma unroll
            for (int n = 0; n < 4; n++)
                pv[n] = exp2f(sfr[n][jj] * 0.18033688f);   // log2(e)/8
            l_part[jj] += (pv[0] + pv[1]) + (pv[2] + pv[3]);
            int r = g * 4 + jj;
#pragma unroll
            for (int n = 0; n < 4; n++)
                Pl[w][r][swz(r, n * 16 + c)] = f2bh(pv[n]);
        }

        __builtin_amdgcn_s_setprio(1);
#pragma unroll
        for (int ks = 0; ks < 2; ks++) {
            short8 vb[4];
#pragma unroll
            for (int dn = 0; dn < 4; dn++)
                vb[dn] = *(const short8*)&Vt[cur][dn * 16 + c][swz(dn * 16 + c, ks * 32 + g * 8)];
            const short8 pa = *(const short8*)&Pl[w][c][swz(c, ks * 32 + g * 8)];
#pragma unroll
            for (int dn = 0; dn < 4; dn++)
                oacc[dn] = mfma16(pa, vb[dn], oacc[dn]);
        }
        __builtin_amdgcn_s_setprio(0);
        __syncthreads();
    }

#pragma unroll
    for (int jj = 0; jj < 4; jj++) {
        float lv = l_part[jj];
#pragma unroll
        for (int msk = 1; msk < 16; msk <<= 1) lv += __shfl_xor(lv, msk);
        float inv = 1.f / lv;
        size_t ro = ((size_t)bb * S_ + qt * 64 + w * 16 + g * 4 + jj) * E_ + hh * DK_;
#pragma unroll
        for (int dn = 0; dn < 4; dn++)
            out[ro + dn * 16 + c] = f2bh(oacc[dn][jj] * inv);
    }
}

// ---------------------------------------------------------------------------
// bf16 GEMM via global_load_lds staging. 64x64 tile, BK=64, dbuf LDS,
// one barrier/step. Wave w stages rows w*16..w*16+15 of A and BT as two
// 1KB chunks; lane l -> row +(l>>3), colblock (l&7)^((l>>3)&7) (inverse
// swizzle at the SOURCE so the swz() read side is unchanged — rule #21).
// ---------------------------------------------------------------------------
__global__ __launch_bounds__(256) void gemm_bf16(const bf16* __restrict__ A,
                                                 const bf16* __restrict__ BT,
                                                 const float* __restrict__ bias,
                                                 bf16* __restrict__ C,
                                                 int M, int N, int K) {
    __shared__ __align__(16) bf16 As2[2][64][64];
    __shared__ __align__(16) bf16 Bs2[2][64][64];
    int nbx = gridDim.x, nwg = nbx * gridDim.y;
    int id = blockIdx.y * nbx + blockIdx.x;
    int id2 = (nwg & 7) ? id : ((id & 7) * (nwg >> 3) + (id >> 3));
    int row0 = (id2 / nbx) * 64, col0 = (id2 % nbx) * 64;
    int t = threadIdx.x, w = t >> 6, l = t & 63, c = l & 15, g = l >> 4;

    f32x4 acc[4];
#pragma unroll
    for (int n = 0; n < 4; n++) acc[n] = (f32x4){0.f, 0.f, 0.f, 0.f};

    // per-lane staging source (inverse-swizzled column block)
    int srow = w * 16 + (l >> 3);
    int scol = ((l & 7) ^ ((l >> 3) & 7)) * 8;
    const bf16* apR0 = A + (size_t)(row0 + srow) * K + scol;
    const bf16* apR1 = A + (size_t)(row0 + srow + 8) * K + scol;
    const bf16* bpR0 = BT + (size_t)(col0 + srow) * K + scol;
    const bf16* bpR1 = BT + (size_t)(col0 + srow + 8) * K + scol;

    // prologue: stage k0=0 into buf0
    gload16(apR0, &As2[0][w * 16][0]);
    gload16(apR1, &As2[0][w * 16 + 8][0]);
    gload16(bpR0, &Bs2[0][w * 16][0]);
    gload16(bpR1, &Bs2[0][w * 16 + 8][0]);
    __syncthreads();

    int cur = 0;
    for (int k0 = 0; k0 < K; k0 += 64, cur ^= 1) {
        int nxt = cur ^ 1;
        if (k0 + 64 < K) {
            gload16(apR0 + k0 + 64, &As2[nxt][w * 16][0]);
            gload16(apR1 + k0 + 64, &As2[nxt][w * 16 + 8][0]);
            gload16(bpR0 + k0 + 64, &Bs2[nxt][w * 16][0]);
            gload16(bpR1 + k0 + 64, &Bs2[nxt][w * 16 + 8][0]);
        }
#pragma unroll
        for (int kh = 0; kh < 2; kh++) {
            const short8 af = *(const short8*)&As2[cur][w * 16 + c][swz(w * 16 + c, kh * 32 + g * 8)];
#pragma unroll
            for (int n = 0; n < 4; n++) {
                const short8 bfr = *(const short8*)&Bs2[cur][n * 16 + c][swz(n * 16 + c, kh * 32 + g * 8)];
                acc[n] = mfma16(af, bfr, acc[n]);
            }
        }
        __syncthreads();   // drains in-flight gload_lds (vmcnt) + lgkm
    }
#pragma unroll
    for (int jj = 0; jj < 4; jj++) {
        int row = row0 + w * 16 + g * 4 + jj;
#pragma unroll
        for (int n = 0; n < 4; n++) {
            int col = col0 + n * 16 + c;
            C[(size_t)row * N + col] = f2bh(acc[n][jj] + bias[col]);
        }
    }
}

// ---------------------------------------------------------------------------
// GEMM2 with in-kernel h via MFMA; Bs staged via global_load_lds (same
// inverse-swizzle-source scheme); W1t reg-staged dbuf (round-9 path).
// ---------------------------------------------------------------------------
__global__ __launch_bounds__(256) void gemm2_mfma(const float* __restrict__ xln,
                                                  const float* __restrict__ ry,
                                                  const bf16* __restrict__ W1bT,
                                                  const float* __restrict__ b1,
                                                  const bf16* __restrict__ W2bT,
                                                  const float* __restrict__ b2,
                                                  bf16* __restrict__ C) {
    __shared__ __align__(16) bf16 As[64][64];
    __shared__ __align__(16) bf16 Bs[2][64][64];
    __shared__ __align__(16) bf16 W1t[2][64][8];
    __shared__ __align__(16) bf16 qm_s[64][8];
    const int nbx = E_ / 64;                    // 12
    const int nwg = nbx * (B_ * S_ / 64);       // 768
    int id = blockIdx.y * nbx + blockIdx.x;
    int id2 = (id & 7) * (nwg >> 3) + (id >> 3);
    int row0 = (id2 / nbx) * 64, col0 = (id2 % nbx) * 64;
    int t = threadIdx.x, w = t >> 6, l = t & 63, c = l & 15, g = l >> 4;

    if (t < 64) {
        const float* xp = xln + (size_t)(row0 + t) * E_;
#pragma unroll
        for (int i = 0; i < NQ_; i++)
            qm_s[t][i] = f2bh(cosf(xp[i]) * cosf(ry[i]));
    }

    f32x4 acc[4];
#pragma unroll
    for (int n = 0; n < 4; n++) acc[n] = (f32x4){0.f, 0.f, 0.f, 0.f};

    // Bs staging source (inverse-swizzled)
    int srow = w * 16 + (l >> 3);
    int scol = ((l & 7) ^ ((l >> 3) & 7)) * 8;
    const bf16* bpR0 = W2bT + (size_t)(col0 + srow) * FF_ + scol;
    const bf16* bpR1 = W2bT + (size_t)(col0 + srow + 8) * FF_ + scol;

    // prologue
    gload16(bpR0, &Bs[0][w * 16][0]);
    gload16(bpR1, &Bs[0][w * 16 + 8][0]);
    short8 preW;
    if (t < 64) {
        preW = *(const short8*)(W1bT + (size_t)t * NQ_);
        *(short8*)&W1t[0][t][0] = preW;
        preW = *(const short8*)(W1bT + (size_t)(64 + t) * NQ_);
    }
    __syncthreads();

    short8 zz = {0, 0, 0, 0, 0, 0, 0, 0};
    short8 aq = zz;
    if (g == 0) aq = *(const short8*)&qm_s[w * 16 + c][0];

    int cur = 0;
    for (int k0 = 0; k0 < FF_; k0 += 64, cur ^= 1) {
        float b1c[4];
#pragma unroll
        for (int n = 0; n < 4; n++) b1c[n] = b1[k0 + n * 16 + c];

        int nxt = cur ^ 1;
        if (k0 + 64 < FF_) {
            gload16(bpR0 + k0 + 64, &Bs[nxt][w * 16][0]);
            gload16(bpR1 + k0 + 64, &Bs[nxt][w * 16 + 8][0]);
            if (t < 64) *(short8*)&W1t[nxt][t][0] = preW;
        }
        if (k0 + 128 < FF_) {
            if (t < 64) preW = *(const short8*)(W1bT + (size_t)(k0 + 128 + t) * NQ_);
        }

        f32x4 zero4 = {0.f, 0.f, 0.f, 0.f};
#pragma unroll
        for (int n = 0; n < 4; n++) {
            short8 bw = zz;
            if (g == 0) bw = *(const short8*)&W1t[cur][n * 16 + c][0];
            f32x4 hfr = mfma16(aq, bw, zero4);
#pragma unroll
            for (int jj = 0; jj < 4; jj++) {
                float hv = fmaxf(hfr[jj] + b1c[n], 0.f);
                int r = w * 16 + g * 4 + jj;
                As[r][swz(r, n * 16 + c)] = f2bh(hv);
            }
        }

#pragma unroll
        for (int kh = 0; kh < 2; kh++) {
            const short8 af = *(const short8*)&As[w * 16 + c][swz(w * 16 + c, kh * 32 + g * 8)];
#pragma unroll
            for (int n = 0; n < 4; n++) {
                const short8 bfr = *(const short8*)&Bs[cur][n * 16 + c][swz(n * 16 + c, kh * 32 + g * 8)];
                acc[n] = mfma16(af, bfr, acc[n]);
            }
        }
        __syncthreads();
    }
#pragma unroll
    for (int jj = 0; jj < 4; jj++) {
        int row = row0 + w * 16 + g * 4 + jj;
#pragma unroll
        for (int n = 0; n < 4; n++) {
            int col = col0 + n * 16 + c;
            C[(size_t)row * E_ + col] = f2bh(acc[n][jj] + b2[col]);
        }
    }
}

// ---------------------------------------------------------------------------
// Fallback GEMM2 (fused hidden via VALU) — used only if ws too small.
// ---------------------------------------------------------------------------
__global__ __launch_bounds__(256) void gemm2_fused(const float* __restrict__ xln,
                                                   const float* __restrict__ ry,
                                                   const float* __restrict__ W1,
                                                   const float* __restrict__ b1,
                                                   const float* __restrict__ W2,
                                                   const float* __restrict__ b2,
                                                   bf16* __restrict__ C) {
    __shared__ __align__(16) bf16 As[64][64];
    __shared__ __align__(16) bf16 Bst[64][64];
    __shared__ float qmS[64][NQ_];
    int row0 = blockIdx.y * 64, col0 = blockIdx.x * 64;
    int t = threadIdx.x, w = t >> 6, l = t & 63, c = l & 15, g = l >> 4;

    for (int idx = t; idx < 64 * NQ_; idx += 256) {
        int r = idx >> 3, i = idx & 7;
        qmS[r][i] = cosf(xln[(size_t)(row0 + r) * E_ + i]) * cosf(ry[i]);
    }

    f32x4 acc[4];
#pragma unroll
    for (int n = 0; n < 4; n++) acc[n] = (f32x4){0.f, 0.f, 0.f, 0.f};

    int kl = t & 63, rg = (t >> 6) * 16;
    int brow = t >> 4, bcol = (t & 15) * 4;

    for (int k0 = 0; k0 < FF_; k0 += 64) {
        __syncthreads();
        {
            float w1v[NQ_];
#pragma unroll
            for (int i = 0; i < NQ_; i++) w1v[i] = W1[i * FF_ + k0 + kl];
            float b1v = b1[k0 + kl];
#pragma unroll
            for (int r16 = 0; r16 < 16; r16++) {
                int r = rg + r16;
                float sh = b1v;
#pragma unroll
                for (int i = 0; i < NQ_; i++) sh += qmS[r][i] * w1v[i];
                As[r][swz(r, kl)] = f2bh(fmaxf(sh, 0.f));
            }
        }
#pragma unroll
        for (int it = 0; it < 4; it++) {
            int kk = brow + it * 16;
            float4 v = *(const float4*)(W2 + (size_t)(k0 + kk) * E_ + col0 + bcol);
            Bst[bcol + 0][swz(bcol + 0, kk)] = f2bh(v.x);
            Bst[bcol + 1][swz(bcol + 1, kk)] = f2bh(v.y);
            Bst[bcol + 2][swz(bcol + 2, kk)] = f2bh(v.z);
            Bst[bcol + 3][swz(bcol + 3, kk)] = f2bh(v.w);
        }
        __syncthreads();
#pragma unroll
        for (int kh = 0; kh < 2; kh++) {
            const short8 af = *(const short8*)&As[w * 16 + c][swz(w * 16 + c, kh * 32 + g * 8)];
#pragma unroll
            for (int n = 0; n < 4; n++) {
                const short8 bfr = *(const short8*)&Bst[n * 16 + c][swz(n * 16 + c, kh * 32 + g * 8)];
                acc[n] = mfma16(af, bfr, acc[n]);
            }
        }
    }
#pragma unroll
    for (int jj = 0; jj < 4; jj++) {
        int row = row0 + w * 16 + g * 4 + jj;
#pragma unroll
        for (int n = 0; n < 4; n++) {
            int col = col0 + n * 16 + c;
            C[(size_t)row * E_ + col] = f2bh(acc[n][jj] + b2[col]);
        }
    }
}

// ---------------------------------------------------------------------------
// out = LayerNorm(X + Yb) * g + be; Y in bf16.
// ---------------------------------------------------------------------------
__global__ __launch_bounds__(256) void ln_add_b(const float* __restrict__ X,
                                                const bf16* __restrict__ Yb,
                                                const float* __restrict__ g,
                                                const float* __restrict__ be,
                                                float* __restrict__ out) {
    int r = blockIdx.x;
    const size_t off = (size_t)r * E_;
    int t = threadIdx.x;
    float v[3];
    float s = 0.f, s2 = 0.f;
#pragma unroll
    for (int j = 0; j < 3; j++) {
        int e = t + j * 256;
        float val = X[off + e] + __bfloat162float(Yb[off + e]);
        v[j] = val; s += val; s2 += val * val;
    }
#pragma unroll
    for (int msk = 32; msk > 0; msk >>= 1) {
        s += __shfl_xor(s, msk);
        s2 += __shfl_xor(s2, msk);
    }
    __shared__ float red[8];
    int lane = t & 63, wv = t >> 6;
    if (lane == 0) { red[wv] = s; red[4 + wv] = s2; }
    __syncthreads();
    if (t == 0) {
        red[0] = red[0] + red[1] + red[2] + red[3];
        red[4] = red[4] + red[5] + red[6] + red[7];
    }
    __syncthreads();
    float mean = red[0] * (1.f / E_);
    float var = red[4] * (1.f / E_) - mean * mean;
    float inv = rsqrtf(var + EPS_);
#pragma unroll
    for (int j = 0; j < 3; j++) {
        int e = t + j * 256;
        out[off + e] = (v[j] - mean) * inv * g[e] + be[e];
    }
}

// ---------------------------------------------------------------------------
extern "C" void kernel_launch(void* const* d_in, const int* in_sizes, int n_in,
                              void* d_out, int out_size, void* d_ws, size_t ws_size,
                              hipStream_t stream) {
    const float* x   = (const float*)d_in[0];
    const float* W_o = (const float*)d_in[1];
    const float* b_o = (const float*)d_in[2];
    const float* g1  = (const float*)d_in[3];
    const float* be1 = (const float*)d_in[4];
    const float* g2  = (const float*)d_in[5];
    const float* be2 = (const float*)d_in[6];
    const float* ry  = (const float*)d_in[7];
    const float* W1  = (const float*)d_in[8];
    const float* b1  = (const float*)d_in[9];
    const float* W2  = (const float*)d_in[10];
    const float* b2  = (const float*)d_in[11];
    float* out = (float*)d_out;

    const size_t BSE = (size_t)B_ * S_ * E_;
    char* ws = (char*)d_ws;

    const size_t FAST_NEED = 43696128;
    bool fast = ws_size >= FAST_NEED;

    // FAST layout (bytes) — unchanged from round 9.
    bf16* xb    = (bf16*)(ws + 0);
    bf16* attnb = (bf16*)(ws + 6291456);
    bf16* WobT  = fast ? (bf16*)(ws + 12582912) : (bf16*)(ws + 18874368);
    bf16* W2bT  = (bf16*)(ws + 13762560);
    bf16* tmp1b = fast ? (bf16*)(ws + 18481152) : (bf16*)(ws + 12582912);
    float* xln  = (float*)(ws + (fast ? 24772608 : 20054016));
    bf16* W1bT  = (bf16*)(ws + 37355520);
    bf16* xT    = (bf16*)(ws + 37404672);
    bf16* tmp2b = tmp1b;

    if (fast) {
        prep_xall<<<dim3(E_ / 32, B_ * S_ / 32), 256, 0, stream>>>(x, xb, xT);
        transpose_cvt<<<dim3(E_ / 32, FF_ / 32), 256, 0, stream>>>(W2, W2bT, FF_, E_);
        prep_w1t<<<dim3(FF_ / 256), 256, 0, stream>>>(W1, W1bT);
    } else {
        prep_cvt<<<dim3((int)((BSE / 4 + 255) / 256)), 256, 0, stream>>>(x, xb, (int)(BSE / 4));
    }
    transpose_cvt<<<dim3(E_ / 32, E_ / 32), 256, 0, stream>>>(W_o, WobT, E_, E_);

    if (fast)
        attn_kernel<true><<<dim3(B_ * H_ * (S_ / 64)), 256, 0, stream>>>(xb, xT, attnb);
    else
        attn_kernel<false><<<dim3(B_ * H_ * (S_ / 64)), 256, 0, stream>>>(xb, xb, attnb);

    gemm_bf16<<<dim3(E_ / 64, (B_ * S_) / 64), 256, 0, stream>>>(
        attnb, WobT, b_o, tmp1b, B_ * S_, E_, E_);
    ln_add_b<<<dim3(B_ * S_), 256, 0, stream>>>(x, tmp1b, g1, be1, xln);

    if (fast) {
        gemm2_mfma<<<dim3(E_ / 64, (B_ * S_) / 64), 256, 0, stream>>>(
            xln, ry, W1bT, b1, W2bT, b2, tmp2b);
    } else {
        gemm2_fused<<<dim3(E_ / 64, (B_ * S_) / 64), 256, 0, stream>>>(
            xln, ry, W1, b1, W2, b2, tmp2b);
    }
    ln_add_b<<<dim3(B_ * S_), 256, 0, stream>>>(xln, tmp2b, g2, be2, out);
}

// Round 13
// 149.274 us; speedup vs baseline: 1.2474x; 1.1004x over previous
//
#include <hip/hip_runtime.h>
#include <hip/hip_bf16.h>

#define B_  2
#define S_  2048
#define E_  768
#define H_  12
#define DK_ 64
#define NQ_ 8
#define FF_ 3072
#define EPS_ 1e-5f

typedef __attribute__((ext_vector_type(8))) short short8;
typedef __attribute__((ext_vector_type(4))) short shortv4;
typedef __attribute__((ext_vector_type(4))) float f32x4;
typedef __hip_bfloat16 bf16;

__device__ __forceinline__ bf16 f2bh(float f) { return __float2bfloat16(f); }
__device__ __forceinline__ short f2b(float f) {
    bf16 h = __float2bfloat16(f);
    return *reinterpret_cast<short*>(&h);
}
__device__ __forceinline__ float b2f(short s) {
    bf16 h = *reinterpret_cast<bf16*>(&s);
    return __bfloat162float(h);
}

// XOR swizzle, 16B-block granular, within a 64-elem bf16 (128B) LDS row.
__device__ __forceinline__ int swz(int row, int col) {
    return (col & 7) | ((((col >> 3) ^ (row & 7)) & 7) << 3);
}

__device__ __forceinline__ f32x4 mfma16(short8 a, short8 b, f32x4 c) {
    return __builtin_amdgcn_mfma_f32_16x16x32_bf16(a, b, c, 0, 0, 0);
}

// Async global->LDS, 16B/lane; LDS dest = wave-uniform base + lane*16.
__device__ __forceinline__ void gload16(const bf16* g, bf16* l) {
    __builtin_amdgcn_global_load_lds(
        (__attribute__((address_space(1))) void*)g,
        (__attribute__((address_space(3))) void*)l, 16, 0, 0);
}

// ---------------------------------------------------------------------------
// prep: xb = bf16(x) row-major AND xT[b][e][s] transposed. One pass.
// ---------------------------------------------------------------------------
__global__ __launch_bounds__(256) void prep_xall(const float* __restrict__ x,
                                                 bf16* __restrict__ xb,
                                                 bf16* __restrict__ xT) {
    __shared__ float tile[32][33];
    int e0 = blockIdx.x * 32, s0 = blockIdx.y * 32;
    int tx = threadIdx.x & 31, ty = threadIdx.x >> 5;
    int b = s0 >> 11, sl0 = s0 & 2047;
#pragma unroll
    for (int i = 0; i < 4; i++) {
        int row = ty + i * 8;
        float v = x[(size_t)(s0 + row) * E_ + e0 + tx];
        tile[row][tx] = v;
        xb[(size_t)(s0 + row) * E_ + e0 + tx] = f2bh(v);
    }
    __syncthreads();
#pragma unroll
    for (int i = 0; i < 4; i++) {
        int row = ty + i * 8;
        xT[((size_t)b * E_ + e0 + row) * S_ + sl0 + tx] = f2bh(tile[tx][row]);
    }
}

// ---------------------------------------------------------------------------
// prep: xb = bf16(x)  (fallback path only)
// ---------------------------------------------------------------------------
__global__ __launch_bounds__(256) void prep_cvt(const float* __restrict__ x,
                                                bf16* __restrict__ xb, int n4) {
    int i = blockIdx.x * 256 + threadIdx.x;
    if (i >= n4) return;
    float4 f = *(const float4*)(x + (size_t)i * 4);
    short4 sv;
    sv.x = f2b(f.x); sv.y = f2b(f.y); sv.z = f2b(f.z); sv.w = f2b(f.w);
    *(short4*)((short*)xb + (size_t)i * 4) = sv;
}

// ---------------------------------------------------------------------------
// prep: WT[N][K] = bf16(W[K][N])
// ---------------------------------------------------------------------------
__global__ __launch_bounds__(256) void transpose_cvt(const float* __restrict__ W,
                                                     bf16* __restrict__ WT,
                                                     int K, int N) {
    __shared__ float tile[32][33];
    int k0 = blockIdx.y * 32, n0 = blockIdx.x * 32;
    int tx = threadIdx.x & 31, ty = threadIdx.x >> 5;
#pragma unroll
    for (int i = 0; i < 4; i++) {
        int row = ty + i * 8;
        tile[row][tx] = W[(size_t)(k0 + row) * N + n0 + tx];
    }
    __syncthreads();
#pragma unroll
    for (int i = 0; i < 4; i++) {
        int row = ty + i * 8;
        WT[(size_t)(n0 + row) * K + k0 + tx] = f2bh(tile[tx][row]);
    }
}

// ---------------------------------------------------------------------------
// prep: W1bT[k][i] = bf16(W1[i][k])
// ---------------------------------------------------------------------------
__global__ __launch_bounds__(256) void prep_w1t(const float* __restrict__ W1,
                                                bf16* __restrict__ W1bT) {
    int k = blockIdx.x * 256 + threadIdx.x;
    if (k >= FF_) return;
    short8 v;
#pragma unroll
    for (int i = 0; i < NQ_; i++) v[i] = f2b(W1[(size_t)i * FF_ + k]);
    *(short8*)(W1bT + (size_t)k * NQ_) = v;
}

// ---------------------------------------------------------------------------
// MFMA flash attention. SWAPPED QK^T: S^T = mfma(K_frag, Q_frag) puts
// S[q=c][4 consecutive keys] in each lane -> packed 8B Pl stores.
// Q prescaled by log2(e)/8 (no per-tile multiply). Single l accumulator.
// XT path: K and V (from pre-transposed xT) staged via global_load_lds
// with inverse-swizzled per-lane SOURCE (rule #21; scheme from gemm_bf16).
// ---------------------------------------------------------------------------
template<bool XT>
__global__ __launch_bounds__(256) void attn_kernel(const bf16* __restrict__ xb,
                                                   const bf16* __restrict__ xT,
                                                   bf16* __restrict__ out) {
    const int qtiles = S_ / 64;                  // 32
    const int nwg = B_ * H_ * qtiles;            // 768
    const int NT = S_ / 64;
    int o = blockIdx.x;
    int blk = (o & 7) * (nwg >> 3) + (o >> 3);
    int qt = blk % qtiles;
    int hh = (blk / qtiles) % H_;
    int bb = blk / (qtiles * H_);
    const bf16* base = xb + (size_t)bb * S_ * E_ + hh * DK_;
    const bf16* baseT = xT + ((size_t)bb * E_ + hh * DK_) * S_;

    __shared__ __align__(16) bf16 Ks[2][64][64];
    __shared__ __align__(16) bf16 Vt[2][64][64];
    __shared__ __align__(16) bf16 Pl[4][16][64];

    int t = threadIdx.x;
    int w = t >> 6, l = t & 63, c = l & 15, g = l >> 4;

    // Q fragments, prescaled by log2(e)/8
    short8 qf[2];
    {
        const bf16* qp = base + (size_t)(qt * 64 + w * 16 + c) * E_;
#pragma unroll
        for (int kh = 0; kh < 2; kh++) {
            short8 v = *(const short8*)(qp + kh * 32 + g * 8);
#pragma unroll
            for (int j = 0; j < 8; j++) v[j] = f2b(b2f(v[j]) * 0.18033688f);
            qf[kh] = v;
        }
    }

    f32x4 oacc[4];
    float lsum = 0.f;
#pragma unroll
    for (int n = 0; n < 4; n++) oacc[n] = (f32x4){0.f, 0.f, 0.f, 0.f};

    // gload staging geometry (XT): wave w stages rows w*16..w*16+15
    int rr = l >> 3;
    int scol = ((l & 7) ^ (rr & 7)) * 8;
    const bf16* srcK = base + (size_t)(w * 16 + rr) * E_ + scol;
    const bf16* srcV = baseT + (size_t)(w * 16 + rr) * S_ + scol;

    // fallback (non-XT) staging vars
    int skey = t & 63, scb0 = t >> 6;
    short8 preK[2];

    if (XT) {
        gload16(srcK, &Ks[0][w * 16][0]);
        gload16(srcK + 8 * E_, &Ks[0][w * 16 + 8][0]);
        gload16(srcV, &Vt[0][w * 16][0]);
        gload16(srcV + 8 * S_, &Vt[0][w * 16 + 8][0]);
    } else {
#pragma unroll
        for (int it = 0; it < 2; it++)
            preK[it] = *(const short8*)(base + (size_t)skey * E_ + (scb0 + it * 4) * 8);
#pragma unroll
        for (int it = 0; it < 2; it++) {
            int cb = scb0 + it * 4;
            *(short8*)&Ks[0][skey][swz(skey, cb * 8)] = preK[it];
#pragma unroll
            for (int j = 0; j < 8; j++) {
                int d = cb * 8 + j;
                short sv = preK[it][j];
                Vt[0][d][swz(d, skey)] = *reinterpret_cast<bf16*>(&sv);
            }
        }
#pragma unroll
        for (int it = 0; it < 2; it++)
            preK[it] = *(const short8*)(base + (size_t)(64 + skey) * E_ + (scb0 + it * 4) * 8);
    }
    __syncthreads();

    int cur = 0;
    for (int kt = 0; kt < NT; kt++, cur ^= 1) {
        int nxt = cur ^ 1;
        if (kt + 1 < NT) {
            if (XT) {
                const bf16* sK = srcK + (size_t)(kt + 1) * 64 * E_;
                const bf16* sV = srcV + (kt + 1) * 64;
                gload16(sK, &Ks[nxt][w * 16][0]);
                gload16(sK + 8 * E_, &Ks[nxt][w * 16 + 8][0]);
                gload16(sV, &Vt[nxt][w * 16][0]);
                gload16(sV + 8 * S_, &Vt[nxt][w * 16 + 8][0]);
            } else {
#pragma unroll
                for (int it = 0; it < 2; it++) {
                    int cb = scb0 + it * 4;
                    *(short8*)&Ks[nxt][skey][swz(skey, cb * 8)] = preK[it];
#pragma unroll
                    for (int j = 0; j < 8; j++) {
                        int d = cb * 8 + j;
                        short sv = preK[it][j];
                        Vt[nxt][d][swz(d, skey)] = *reinterpret_cast<bf16*>(&sv);
                    }
                }
            }
        }
        if (!XT && kt + 2 < NT) {
#pragma unroll
            for (int it = 0; it < 2; it++)
                preK[it] = *(const short8*)(base + (size_t)((kt + 2) * 64 + skey) * E_ + (scb0 + it * 4) * 8);
        }

        // S^T = K Q^T (swapped operands): lane holds S[q=c][key=n*16+g*4+jj]
        f32x4 sfr[4];
        __builtin_amdgcn_s_setprio(1);
#pragma unroll
        for (int n = 0; n < 4; n++) {
            sfr[n] = (f32x4){0.f, 0.f, 0.f, 0.f};
#pragma unroll
            for (int kh = 0; kh < 2; kh++) {
                const short8 bfr = *(const short8*)&Ks[cur][n * 16 + c][swz(n * 16 + c, kh * 32 + g * 8)];
                sfr[n] = mfma16(bfr, qf[kh], sfr[n]);
            }
        }
        __builtin_amdgcn_s_setprio(0);

        // P = exp2(S'), packed 4-wide store into Pl row q=c
#pragma unroll
        for (int n = 0; n < 4; n++) {
            float pv[4];
#pragma unroll
            for (int jj = 0; jj < 4; jj++) pv[jj] = exp2f(sfr[n][jj]);
            lsum += (pv[0] + pv[1]) + (pv[2] + pv[3]);
            shortv4 pk;
#pragma unroll
            for (int jj = 0; jj < 4; jj++) pk[jj] = f2b(pv[jj]);
            *(shortv4*)&Pl[w][c][swz(c, n * 16 + g * 4)] = pk;
        }

        // O += P V
        __builtin_amdgcn_s_setprio(1);
#pragma unroll
        for (int ks = 0; ks < 2; ks++) {
            short8 vb[4];
#pragma unroll
            for (int dn = 0; dn < 4; dn++)
                vb[dn] = *(const short8*)&Vt[cur][dn * 16 + c][swz(dn * 16 + c, ks * 32 + g * 8)];
            const short8 pa = *(const short8*)&Pl[w][c][swz(c, ks * 32 + g * 8)];
#pragma unroll
            for (int dn = 0; dn < 4; dn++)
                oacc[dn] = mfma16(pa, vb[dn], oacc[dn]);
        }
        __builtin_amdgcn_s_setprio(0);
        __syncthreads();
    }

    // L[q=c] = sum over the 4 g-groups; redistribute to D-layout rows
#pragma unroll
    for (int msk = 16; msk < 64; msk <<= 1) lsum += __shfl_xor(lsum, msk);
#pragma unroll
    for (int jj = 0; jj < 4; jj++) {
        float inv = 1.f / __shfl(lsum, g * 4 + jj);
        size_t ro = ((size_t)bb * S_ + qt * 64 + w * 16 + g * 4 + jj) * E_ + hh * DK_;
#pragma unroll
        for (int dn = 0; dn < 4; dn++)
            out[ro + dn * 16 + c] = f2bh(oacc[dn][jj] * inv);
    }
}

// ---------------------------------------------------------------------------
// bf16 GEMM via global_load_lds staging (unchanged from round 12).
// ---------------------------------------------------------------------------
__global__ __launch_bounds__(256) void gemm_bf16(const bf16* __restrict__ A,
                                                 const bf16* __restrict__ BT,
                                                 const float* __restrict__ bias,
                                                 bf16* __restrict__ C,
                                                 int M, int N, int K) {
    __shared__ __align__(16) bf16 As2[2][64][64];
    __shared__ __align__(16) bf16 Bs2[2][64][64];
    int nbx = gridDim.x, nwg = nbx * gridDim.y;
    int id = blockIdx.y * nbx + blockIdx.x;
    int id2 = (nwg & 7) ? id : ((id & 7) * (nwg >> 3) + (id >> 3));
    int row0 = (id2 / nbx) * 64, col0 = (id2 % nbx) * 64;
    int t = threadIdx.x, w = t >> 6, l = t & 63, c = l & 15, g = l >> 4;

    f32x4 acc[4];
#pragma unroll
    for (int n = 0; n < 4; n++) acc[n] = (f32x4){0.f, 0.f, 0.f, 0.f};

    int srow = w * 16 + (l >> 3);
    int scol = ((l & 7) ^ ((l >> 3) & 7)) * 8;
    const bf16* apR0 = A + (size_t)(row0 + srow) * K + scol;
    const bf16* apR1 = A + (size_t)(row0 + srow + 8) * K + scol;
    const bf16* bpR0 = BT + (size_t)(col0 + srow) * K + scol;
    const bf16* bpR1 = BT + (size_t)(col0 + srow + 8) * K + scol;

    gload16(apR0, &As2[0][w * 16][0]);
    gload16(apR1, &As2[0][w * 16 + 8][0]);
    gload16(bpR0, &Bs2[0][w * 16][0]);
    gload16(bpR1, &Bs2[0][w * 16 + 8][0]);
    __syncthreads();

    int cur = 0;
    for (int k0 = 0; k0 < K; k0 += 64, cur ^= 1) {
        int nxt = cur ^ 1;
        if (k0 + 64 < K) {
            gload16(apR0 + k0 + 64, &As2[nxt][w * 16][0]);
            gload16(apR1 + k0 + 64, &As2[nxt][w * 16 + 8][0]);
            gload16(bpR0 + k0 + 64, &Bs2[nxt][w * 16][0]);
            gload16(bpR1 + k0 + 64, &Bs2[nxt][w * 16 + 8][0]);
        }
#pragma unroll
        for (int kh = 0; kh < 2; kh++) {
            const short8 af = *(const short8*)&As2[cur][w * 16 + c][swz(w * 16 + c, kh * 32 + g * 8)];
#pragma unroll
            for (int n = 0; n < 4; n++) {
                const short8 bfr = *(const short8*)&Bs2[cur][n * 16 + c][swz(n * 16 + c, kh * 32 + g * 8)];
                acc[n] = mfma16(af, bfr, acc[n]);
            }
        }
        __syncthreads();
    }
#pragma unroll
    for (int jj = 0; jj < 4; jj++) {
        int row = row0 + w * 16 + g * 4 + jj;
#pragma unroll
        for (int n = 0; n < 4; n++) {
            int col = col0 + n * 16 + c;
            C[(size_t)row * N + col] = f2bh(acc[n][jj] + bias[col]);
        }
    }
}

// ---------------------------------------------------------------------------
// GEMM2 with in-kernel h via SWAPPED MFMA: h^T = mfma(W1_frag, qm_frag)
// puts h[q=c][4 consecutive k] per lane -> packed 8B As stores (was 16
// scalar). Bs staged via global_load_lds; W1t reg-staged dbuf.
// ---------------------------------------------------------------------------
__global__ __launch_bounds__(256) void gemm2_mfma(const float* __restrict__ xln,
                                                  const float* __restrict__ ry,
                                                  const bf16* __restrict__ W1bT,
                                                  const float* __restrict__ b1,
                                                  const bf16* __restrict__ W2bT,
                                                  const float* __restrict__ b2,
                                                  bf16* __restrict__ C) {
    __shared__ __align__(16) bf16 As[64][64];
    __shared__ __align__(16) bf16 Bs[2][64][64];
    __shared__ __align__(16) bf16 W1t[2][64][8];
    __shared__ __align__(16) bf16 qm_s[64][8];
    const int nbx = E_ / 64;                    // 12
    const int nwg = nbx * (B_ * S_ / 64);       // 768
    int id = blockIdx.y * nbx + blockIdx.x;
    int id2 = (id & 7) * (nwg >> 3) + (id >> 3);
    int row0 = (id2 / nbx) * 64, col0 = (id2 % nbx) * 64;
    int t = threadIdx.x, w = t >> 6, l = t & 63, c = l & 15, g = l >> 4;

    if (t < 64) {
        const float* xp = xln + (size_t)(row0 + t) * E_;
#pragma unroll
        for (int i = 0; i < NQ_; i++)
            qm_s[t][i] = f2bh(cosf(xp[i]) * cosf(ry[i]));
    }

    f32x4 acc[4];
#pragma unroll
    for (int n = 0; n < 4; n++) acc[n] = (f32x4){0.f, 0.f, 0.f, 0.f};

    int srow = w * 16 + (l >> 3);
    int scol = ((l & 7) ^ ((l >> 3) & 7)) * 8;
    const bf16* bpR0 = W2bT + (size_t)(col0 + srow) * FF_ + scol;
    const bf16* bpR1 = W2bT + (size_t)(col0 + srow + 8) * FF_ + scol;

    gload16(bpR0, &Bs[0][w * 16][0]);
    gload16(bpR1, &Bs[0][w * 16 + 8][0]);
    short8 preW;
    if (t < 64) {
        preW = *(const short8*)(W1bT + (size_t)t * NQ_);
        *(short8*)&W1t[0][t][0] = preW;
        preW = *(const short8*)(W1bT + (size_t)(64 + t) * NQ_);
    }
    __syncthreads();

    short8 zz = {0, 0, 0, 0, 0, 0, 0, 0};
    short8 aq = zz;
    if (g == 0) aq = *(const short8*)&qm_s[w * 16 + c][0];

    int cur = 0;
    for (int k0 = 0; k0 < FF_; k0 += 64, cur ^= 1) {
        // b1 slices, k-contiguous (h^T lane holds k = n*16+g*4+jj)
        f32x4 b1v[4];
#pragma unroll
        for (int n = 0; n < 4; n++)
            b1v[n] = *(const f32x4*)(b1 + k0 + n * 16 + g * 4);

        int nxt = cur ^ 1;
        if (k0 + 64 < FF_) {
            gload16(bpR0 + k0 + 64, &Bs[nxt][w * 16][0]);
            gload16(bpR1 + k0 + 64, &Bs[nxt][w * 16 + 8][0]);
            if (t < 64) *(short8*)&W1t[nxt][t][0] = preW;
        }
        if (k0 + 128 < FF_) {
            if (t < 64) preW = *(const short8*)(W1bT + (size_t)(k0 + 128 + t) * NQ_);
        }

        f32x4 zero4 = {0.f, 0.f, 0.f, 0.f};
        int r = w * 16 + c;
#pragma unroll
        for (int n = 0; n < 4; n++) {
            short8 bw = zz;
            if (g == 0) bw = *(const short8*)&W1t[cur][n * 16 + c][0];
            f32x4 hfr = mfma16(bw, aq, zero4);   // swapped: h[q=c][k consec]
            shortv4 pk;
#pragma unroll
            for (int jj = 0; jj < 4; jj++)
                pk[jj] = f2b(fmaxf(hfr[jj] + b1v[n][jj], 0.f));
            *(shortv4*)&As[r][swz(r, n * 16 + g * 4)] = pk;
        }

#pragma unroll
        for (int kh = 0; kh < 2; kh++) {
            const short8 af = *(const short8*)&As[w * 16 + c][swz(w * 16 + c, kh * 32 + g * 8)];
#pragma unroll
            for (int n = 0; n < 4; n++) {
                const short8 bfr = *(const short8*)&Bs[cur][n * 16 + c][swz(n * 16 + c, kh * 32 + g * 8)];
                acc[n] = mfma16(af, bfr, acc[n]);
            }
        }
        __syncthreads();
    }
#pragma unroll
    for (int jj = 0; jj < 4; jj++) {
        int row = row0 + w * 16 + g * 4 + jj;
#pragma unroll
        for (int n = 0; n < 4; n++) {
            int col = col0 + n * 16 + c;
            C[(size_t)row * E_ + col] = f2bh(acc[n][jj] + b2[col]);
        }
    }
}

// ---------------------------------------------------------------------------
// Fallback GEMM2 (fused hidden via VALU) — used only if ws too small.
// ---------------------------------------------------------------------------
__global__ __launch_bounds__(256) void gemm2_fused(const float* __restrict__ xln,
                                                   const float* __restrict__ ry,
                                                   const float* __restrict__ W1,
                                                   const float* __restrict__ b1,
                                                   const float* __restrict__ W2,
                                                   const float* __restrict__ b2,
                                                   bf16* __restrict__ C) {
    __shared__ __align__(16) bf16 As[64][64];
    __shared__ __align__(16) bf16 Bst[64][64];
    __shared__ float qmS[64][NQ_];
    int row0 = blockIdx.y * 64, col0 = blockIdx.x * 64;
    int t = threadIdx.x, w = t >> 6, l = t & 63, c = l & 15, g = l >> 4;

    for (int idx = t; idx < 64 * NQ_; idx += 256) {
        int r = idx >> 3, i = idx & 7;
        qmS[r][i] = cosf(xln[(size_t)(row0 + r) * E_ + i]) * cosf(ry[i]);
    }

    f32x4 acc[4];
#pragma unroll
    for (int n = 0; n < 4; n++) acc[n] = (f32x4){0.f, 0.f, 0.f, 0.f};

    int kl = t & 63, rg = (t >> 6) * 16;
    int brow = t >> 4, bcol = (t & 15) * 4;

    for (int k0 = 0; k0 < FF_; k0 += 64) {
        __syncthreads();
        {
            float w1v[NQ_];
#pragma unroll
            for (int i = 0; i < NQ_; i++) w1v[i] = W1[i * FF_ + k0 + kl];
            float b1v = b1[k0 + kl];
#pragma unroll
            for (int r16 = 0; r16 < 16; r16++) {
                int r = rg + r16;
                float sh = b1v;
#pragma unroll
                for (int i = 0; i < NQ_; i++) sh += qmS[r][i] * w1v[i];
                As[r][swz(r, kl)] = f2bh(fmaxf(sh, 0.f));
            }
        }
#pragma unroll
        for (int it = 0; it < 4; it++) {
            int kk = brow + it * 16;
            float4 v = *(const float4*)(W2 + (size_t)(k0 + kk) * E_ + col0 + bcol);
            Bst[bcol + 0][swz(bcol + 0, kk)] = f2bh(v.x);
            Bst[bcol + 1][swz(bcol + 1, kk)] = f2bh(v.y);
            Bst[bcol + 2][swz(bcol + 2, kk)] = f2bh(v.z);
            Bst[bcol + 3][swz(bcol + 3, kk)] = f2bh(v.w);
        }
        __syncthreads();
#pragma unroll
        for (int kh = 0; kh < 2; kh++) {
            const short8 af = *(const short8*)&As[w * 16 + c][swz(w * 16 + c, kh * 32 + g * 8)];
#pragma unroll
            for (int n = 0; n < 4; n++) {
                const short8 bfr = *(const short8*)&Bst[n * 16 + c][swz(n * 16 + c, kh * 32 + g * 8)];
                acc[n] = mfma16(af, bfr, acc[n]);
            }
        }
    }
#pragma unroll
    for (int jj = 0; jj < 4; jj++) {
        int row = row0 + w * 16 + g * 4 + jj;
#pragma unroll
        for (int n = 0; n < 4; n++) {
            int col = col0 + n * 16 + c;
            C[(size_t)row * E_ + col] = f2bh(acc[n][jj] + b2[col]);
        }
    }
}

// ---------------------------------------------------------------------------
// out = LayerNorm(X + Yb) * g + be; Y in bf16.
// ---------------------------------------------------------------------------
__global__ __launch_bounds__(256) void ln_add_b(const float* __restrict__ X,
                                                const bf16* __restrict__ Yb,
                                                const float* __restrict__ g,
                                                const float* __restrict__ be,
                                                float* __restrict__ out) {
    int r = blockIdx.x;
    const size_t off = (size_t)r * E_;
    int t = threadIdx.x;
    float v[3];
    float s = 0.f, s2 = 0.f;
#pragma unroll
    for (int j = 0; j < 3; j++) {
        int e = t + j * 256;
        float val = X[off + e] + __bfloat162float(Yb[off + e]);
        v[j] = val; s += val; s2 += val * val;
    }
#pragma unroll
    for (int msk = 32; msk > 0; msk >>= 1) {
        s += __shfl_xor(s, msk);
        s2 += __shfl_xor(s2, msk);
    }
    __shared__ float red[8];
    int lane = t & 63, wv = t >> 6;
    if (lane == 0) { red[wv] = s; red[4 + wv] = s2; }
    __syncthreads();
    if (t == 0) {
        red[0] = red[0] + red[1] + red[2] + red[3];
        red[4] = red[4] + red[5] + red[6] + red[7];
    }
    __syncthreads();
    float mean = red[0] * (1.f / E_);
    float var = red[4] * (1.f / E_) - mean * mean;
    float inv = rsqrtf(var + EPS_);
#pragma unroll
    for (int j = 0; j < 3; j++) {
        int e = t + j * 256;
        out[off + e] = (v[j] - mean) * inv * g[e] + be[e];
    }
}

// ---------------------------------------------------------------------------
extern "C" void kernel_launch(void* const* d_in, const int* in_sizes, int n_in,
                              void* d_out, int out_size, void* d_ws, size_t ws_size,
                              hipStream_t stream) {
    const float* x   = (const float*)d_in[0];
    const float* W_o = (const float*)d_in[1];
    const float* b_o = (const float*)d_in[2];
    const float* g1  = (const float*)d_in[3];
    const float* be1 = (const float*)d_in[4];
    const float* g2  = (const float*)d_in[5];
    const float* be2 = (const float*)d_in[6];
    const float* ry  = (const float*)d_in[7];
    const float* W1  = (const float*)d_in[8];
    const float* b1  = (const float*)d_in[9];
    const float* W2  = (const float*)d_in[10];
    const float* b2  = (const float*)d_in[11];
    float* out = (float*)d_out;

    const size_t BSE = (size_t)B_ * S_ * E_;
    char* ws = (char*)d_ws;

    const size_t FAST_NEED = 43696128;
    bool fast = ws_size >= FAST_NEED;

    // FAST layout (bytes) — unchanged from round 9.
    bf16* xb    = (bf16*)(ws + 0);
    bf16* attnb = (bf16*)(ws + 6291456);
    bf16* WobT  = fast ? (bf16*)(ws + 12582912) : (bf16*)(ws + 18874368);
    bf16* W2bT  = (bf16*)(ws + 13762560);
    bf16* tmp1b = fast ? (bf16*)(ws + 18481152) : (bf16*)(ws + 12582912);
    float* xln  = (float*)(ws + (fast ? 24772608 : 20054016));
    bf16* W1bT  = (bf16*)(ws + 37355520);
    bf16* xT    = (bf16*)(ws + 37404672);
    bf16* tmp2b = tmp1b;

    if (fast) {
        prep_xall<<<dim3(E_ / 32, B_ * S_ / 32), 256, 0, stream>>>(x, xb, xT);
        transpose_cvt<<<dim3(E_ / 32, FF_ / 32), 256, 0, stream>>>(W2, W2bT, FF_, E_);
        prep_w1t<<<dim3(FF_ / 256), 256, 0, stream>>>(W1, W1bT);
    } else {
        prep_cvt<<<dim3((int)((BSE / 4 + 255) / 256)), 256, 0, stream>>>(x, xb, (int)(BSE / 4));
    }
    transpose_cvt<<<dim3(E_ / 32, E_ / 32), 256, 0, stream>>>(W_o, WobT, E_, E_);

    if (fast)
        attn_kernel<true><<<dim3(B_ * H_ * (S_ / 64)), 256, 0, stream>>>(xb, xT, attnb);
    else
        attn_kernel<false><<<dim3(B_ * H_ * (S_ / 64)), 256, 0, stream>>>(xb, xb, attnb);

    gemm_bf16<<<dim3(E_ / 64, (B_ * S_) / 64), 256, 0, stream>>>(
        attnb, WobT, b_o, tmp1b, B_ * S_, E_, E_);
    ln_add_b<<<dim3(B_ * S_), 256, 0, stream>>>(x, tmp1b, g1, be1, xln);

    if (fast) {
        gemm2_mfma<<<dim3(E_ / 64, (B_ * S_) / 64), 256, 0, stream>>>(
            xln, ry, W1bT, b1, W2bT, b2, tmp2b);
    } else {
        gemm2_fused<<<dim3(E_ / 64, (B_ * S_) / 64), 256, 0, stream>>>(
            xln, ry, W1, b1, W2, b2, tmp2b);
    }
    ln_add_b<<<dim3(B_ * S_), 256, 0, stream>>>(xln, tmp2b, g2, be2, out);
}